// Round 15
// baseline (800.197 us; speedup 1.0000x reference)
//
#include <hip/hip_runtime.h>
#include <hip/hip_fp8.h>
#include <cstdint>

#define CDIV(a,b) (((a)+(b)-1)/(b))

typedef __attribute__((ext_vector_type(8))) short bf16x8;     // 8 bf16 = 4 VGPRs
typedef __attribute__((ext_vector_type(4))) float f32x4;      // MFMA accumulator
typedef __attribute__((ext_vector_type(8))) float f32x8;
typedef __attribute__((ext_vector_type(4))) _Float16 half4;
typedef __attribute__((ext_vector_type(8))) _Float16 half8;   // 16B fp16 vector

// Q/K/V stored fp8-e4m3 scaled by QK_SCALE.
#define QK_SCALE 32.0f
#define SCORE_SCALE (0.25f / (QK_SCALE * QK_SCALE))
#define EXP2_C (SCORE_SCALE * 1.44269504089f)

// Entity features stored fp8-e4m3 scaled by ES_SCALE.
#define ES_SCALE 64.0f

__device__ __forceinline__ float bf2f(short s) {
    return __builtin_bit_cast(float, ((unsigned)(unsigned short)s) << 16);
}
__device__ __forceinline__ short rtne(float f) {
    const unsigned u = __builtin_bit_cast(unsigned, f);
    return (short)((u + 0x7fffu + ((u >> 16) & 1u)) >> 16);
}
__device__ __forceinline__ unsigned pack2r(float lo, float hi) {
    return (unsigned)(unsigned short)rtne(lo) | ((unsigned)(unsigned short)rtne(hi) << 16);
}
__device__ __forceinline__ float fp8tof(unsigned char b) {
    __hip_fp8_e4m3 t; t.__x = b; return (float)t;
}
__device__ __forceinline__ unsigned char ftofp8(float f) {
    __hip_fp8_e4m3 t(f); return t.__x;
}
__device__ __forceinline__ f32x8 fp8x8tof32(long v) {
    union { long l; unsigned char b[8]; } u; u.l = v;
    f32x8 r;
    #pragma unroll
    for (int j = 0; j < 8; ++j) r[j] = fp8tof(u.b[j]);
    return r;
}
__device__ __forceinline__ long f32x8tofp8(f32x8 a) {
    union { long l; unsigned char b[8]; } u;
    #pragma unroll
    for (int j = 0; j < 8; ++j) u.b[j] = ftofp8(a[j]);
    return u.l;
}

// DPP row-of-16 sum: result valid at (lane&15)==0. VALU-only (no LDS pipe).
template<int CTRL>
__device__ __forceinline__ float dpp_add(float x) {
    const int t = __builtin_amdgcn_update_dpp(0, __builtin_bit_cast(int, x),
                                              CTRL, 0xf, 0xf, true);
    return x + __builtin_bit_cast(float, t);
}
__device__ __forceinline__ float rowsum16(float x) {
    x = dpp_add<0x108>(x);   // row_shl:8
    x = dpp_add<0x104>(x);   // row_shl:4
    x = dpp_add<0x102>(x);   // row_shl:2
    x = dpp_add<0x101>(x);   // row_shl:1
    return x;
}

// ---------------------------------------------------------------------------
// Device bodies (block-range fused dispatch).
// ---------------------------------------------------------------------------

// MFMA prep. Table row (192 B): [K fp8 64B][Q fp8 64B][V fp8 64B].
// High VGPR — only fused with scan_reduce/edge-expand (occupancy-insensitive).
__device__ __forceinline__ void prep_body(int bid,
    const float* __restrict__ we, const short* __restrict__ Wt,
    const float* __restrict__ bq, const float* __restrict__ bk,
    const float* __restrict__ bv, unsigned char* __restrict__ WQKV, int NW)
{
    const int wave = threadIdx.x >> 6;
    const int lane = threadIdx.x & 63;
    const int quad = lane >> 4;
    const int lm   = lane & 15;
    const int ntiles = CDIV(NW, 16);

    bf16x8 bfr[3][4][2];
    #pragma unroll
    for (int p = 0; p < 3; ++p)
        #pragma unroll
        for (int nt = 0; nt < 4; ++nt)
            #pragma unroll
            for (int kh = 0; kh < 2; ++kh)
                bfr[p][nt][kh] = *(const bf16x8*)(Wt + ((p*64 + nt*16 + lm)*64) + kh*32 + quad*8);
    float bias[3][4];
    #pragma unroll
    for (int nt = 0; nt < 4; ++nt) {
        bias[0][nt] = bq[nt*16 + lm];
        bias[1][nt] = bk[nt*16 + lm];
        bias[2][nt] = bv[nt*16 + lm];
    }

    #pragma unroll
    for (int t = 0; t < 4; ++t) {
        const int tile = (bid*4 + wave)*4 + t;
        if (tile >= ntiles) return;
        const int wb = tile*16;
        int w = wb + lm;
        if (w >= NW) w = NW - 1;
        const float* xr = we + (size_t)w*64;
        union { unsigned u[4]; bf16x8 v; } a0, a1;
        const float4 f0 = *(const float4*)(xr + quad*8);
        const float4 f1 = *(const float4*)(xr + quad*8 + 4);
        const float4 f2 = *(const float4*)(xr + 32 + quad*8);
        const float4 f3 = *(const float4*)(xr + 32 + quad*8 + 4);
        a0.u[0] = pack2r(f0.x, f0.y); a0.u[1] = pack2r(f0.z, f0.w);
        a0.u[2] = pack2r(f1.x, f1.y); a0.u[3] = pack2r(f1.z, f1.w);
        a1.u[0] = pack2r(f2.x, f2.y); a1.u[1] = pack2r(f2.z, f2.w);
        a1.u[2] = pack2r(f3.x, f3.y); a1.u[3] = pack2r(f3.z, f3.w);
        if (w == 0) {
            a0.u[0]=0u; a0.u[1]=0u; a0.u[2]=0u; a0.u[3]=0u;
            a1.u[0]=0u; a1.u[1]=0u; a1.u[2]=0u; a1.u[3]=0u;
        }
        #pragma unroll
        for (int p = 0; p < 3; ++p) {
            #pragma unroll
            for (int nt = 0; nt < 4; ++nt) {
                f32x4 c = {bias[p][nt], bias[p][nt], bias[p][nt], bias[p][nt]};
                c = __builtin_amdgcn_mfma_f32_16x16x32_bf16(a0.v, bfr[p][nt][0], c, 0, 0, 0);
                c = __builtin_amdgcn_mfma_f32_16x16x32_bf16(a1.v, bfr[p][nt][1], c, 0, 0, 0);
                #pragma unroll
                for (int r = 0; r < 4; ++r) {
                    const int w2 = wb + quad*4 + r;
                    if (w2 < NW) {
                        unsigned char* rowo = WQKV + (size_t)w2*192;
                        const int base = (p == 2) ? 128 : (p == 0) ? 64 : 0;
                        rowo[base + nt*16 + lm] = ftofp8(c[r] * QK_SCALE);
                    }
                }
            }
        }
    }
}

// Combined CSR fill: int2 entries. dst-side = (src, qid); src-side = (dst|FLAG, 0).
__device__ __forceinline__ void fill_body(int bid,
    const int* __restrict__ src, const int* __restrict__ dst,
    const int* __restrict__ qid,
    int* __restrict__ curC, int2* __restrict__ cmb2, int EP)
{
    const int t = bid*256 + threadIdx.x;
    if (t >= EP) return;
    const int s = src[t], d = dst[t];
    const int p1 = atomicAdd(&curC[d], 1);
    int2 e1; e1.x = s; e1.y = qid[t];
    cmb2[p1] = e1;
    const int p2 = atomicAdd(&curC[s], 1);
    int2 e2; e2.x = d | (int)0x80000000; e2.y = 0;
    cmb2[p2] = e2;
}

// Edge-parallel frontier expand (no CSR needed — reads pur_src/pur_dst).
// Race-free: lev only grows; the lev>=targ+1 predicate set is frozen before
// the pass; atomicMax old-value dedups appends exactly once.
__device__ __forceinline__ void eexp_body(int bid, int nb, unsigned targ,
    const int* __restrict__ src, const int* __restrict__ dst, int EP,
    unsigned* __restrict__ lev,
    int* __restrict__ dl1, int* __restrict__ dn1,
    int* __restrict__ dl2, int* __restrict__ dn2)
{
    const int stride = nb * 256;
    for (int t = bid*256 + threadIdx.x; t < EP; t += stride) {
        const int s = src[t], d = dst[t];
        const unsigned ls = lev[s], ld = lev[d];
        if (ls > targ && ld < targ) {
            const unsigned old = atomicMax(&lev[d], targ);
            if (old < targ) {
                dl1[atomicAdd(dn1, 1)] = d;
                if (dl2) dl2[atomicAdd(dn2, 1)] = d;
            }
        }
        if (ld > targ && ls < targ) {
            const unsigned old = atomicMax(&lev[s], targ);
            if (old < targ) {
                dl1[atomicAdd(dn1, 1)] = s;
                if (dl2) dl2[atomicAdd(dn2, 1)] = s;
            }
        }
    }
}

// e8[v] = fp8(ES_SCALE * [entity_emb[v] | prof[v]/max(deg_p,1)]); inv = 1/sqrt(cntC)
__device__ __forceinline__ void finalize_body(int bid,
    const float* __restrict__ emb, const float* __restrict__ prof,
    unsigned char* __restrict__ e8, float* __restrict__ inv,
    const unsigned* __restrict__ deg_p, const unsigned* __restrict__ cntC, int NE)
{
    const int t = bid*256 + threadIdx.x;
    const int v = t >> 5;
    if (v >= NE) return;
    const int c = (t & 31) * 4;
    float4 ev;
    if (c < 64) {
        ev = *(const float4*)&emb[(size_t)v*64 + c];
    } else {
        ev = *(const float4*)&prof[(size_t)v*64 + (c - 64)];
        const unsigned dp = deg_p[v];
        const float r = 1.0f / (float)(dp > 1u ? dp : 1u);
        ev.x *= r; ev.y *= r; ev.z *= r; ev.w *= r;
    }
    union { unsigned u; unsigned char b[4]; } pk;
    pk.b[0] = ftofp8(ev.x * ES_SCALE);
    pk.b[1] = ftofp8(ev.y * ES_SCALE);
    pk.b[2] = ftofp8(ev.z * ES_SCALE);
    pk.b[3] = ftofp8(ev.w * ES_SCALE);
    *(unsigned*)&e8[(size_t)v*128 + c] = pk.u;
    if (c == 0) {
        const unsigned di = cntC[v];
        inv[v] = 1.0f / sqrtf((float)(di > 1u ? di : 1u));
    }
}

// acc[r] += e8[sel[r]] (scaled domain)
__device__ __forceinline__ void gather_body(int bid,
    const unsigned char* __restrict__ e8, const int* __restrict__ users,
    const int* __restrict__ items, const int* __restrict__ negs,
    float* __restrict__ acc, int B)
{
    const int t = bid*256 + threadIdx.x;
    const int r = t >> 4;
    if (r >= 3*B) return;
    const int c = (t & 15) * 8;
    const int which = r / B, b = r - which*B;
    const int idx = (which == 0) ? users[b] : (which == 1) ? items[b] : negs[b];
    const long ev = *(const long*)&e8[(size_t)idx*128 + c];
    f32x8 a = *(const f32x8*)&acc[(size_t)r*128 + c];
    a += fp8x8tof32(ev);
    *(f32x8*)&acc[(size_t)r*128 + c] = a;
}

// Fused e1-prop + qconst over list1: one CSR traversal computes both the
// q-term (dst-side entries, lanes c>=64) and the e-gather term; qc written
// for the later hops, unrounded q-sum seeds the e1 accumulator.
__device__ __forceinline__ void prop1_body(int bid, int nb,
    const unsigned char* __restrict__ e_cur, const _Float16* __restrict__ q_h16,
    const float* __restrict__ inv,
    const int* __restrict__ offC, const int* __restrict__ endC,
    const int2* __restrict__ cmb2,
    const int* __restrict__ list, const int* __restrict__ pn,
    unsigned char* __restrict__ e_nxt, _Float16* __restrict__ qc)
{
    const int n = *pn;
    const int stride = nb * 256;
    for (int t = bid*256 + threadIdx.x; (t >> 4) < n; t += stride) {
        const int v = list[t >> 4];
        const int c = (t & 15) * 8;
        const bool qlane = (c >= 64);
        f32x8 a  = {0.f,0.f,0.f,0.f,0.f,0.f,0.f,0.f};
        f32x8 qa = {0.f,0.f,0.f,0.f,0.f,0.f,0.f,0.f};
        const int b0 = offC[v], e0 = endC[v];
        for (int i = b0; i < e0; ++i) {
            const int2 e = cmb2[i];
            const int u = e.x & 0x7fffffff;
            const float w = (e.x < 0) ? inv[u] : 1.0f;
            a += fp8x8tof32(*(const long*)&e_cur[(size_t)u*128 + c]) * w;
            if (e.x >= 0 && qlane) {
                const half8 qh = *(const half8*)&q_h16[(size_t)e.y*64 + (c - 64)];
                qa += __builtin_convertvector(qh, f32x8) * inv[u];
            }
        }
        if (qlane) {
            qa *= ES_SCALE;
            *(half8*)&qc[(size_t)v*64 + (c - 64)] = __builtin_convertvector(qa, half8);
            a += qa;
        }
        a *= inv[v];
        *(long*)&e_nxt[(size_t)v*128 + c] = f32x8tofp8(a);
    }
}

// Propagate+combine over the merged list (qc precomputed), for e2.
__device__ __forceinline__ void prop_list_body(int bid, int nb,
    const unsigned char* __restrict__ e_cur, const _Float16* __restrict__ qc,
    const float* __restrict__ inv,
    const int* __restrict__ offC, const int* __restrict__ endC,
    const int2* __restrict__ cmb2,
    const int* __restrict__ list, const int* __restrict__ pn,
    unsigned char* __restrict__ e_nxt)
{
    const int n = *pn;
    const int stride = nb * 256;
    for (int t = bid*256 + threadIdx.x; (t >> 4) < n; t += stride) {
        const int v = list[t >> 4];
        const int c = (t & 15) * 8;
        f32x8 a = {0.f,0.f,0.f,0.f,0.f,0.f,0.f,0.f};
        if (c >= 64) {
            const half8 q = *(const half8*)&qc[(size_t)v*64 + (c - 64)];
            a = __builtin_convertvector(q, f32x8);
        }
        const int b0 = offC[v], e0 = endC[v];
        int un = (b0 < e0) ? cmb2[b0].x : 0;
        for (int i = b0; i < e0; ++i) {
            const int uc = un;
            if (i + 1 < e0) un = cmb2[i + 1].x;
            const int u = uc & 0x7fffffff;
            const long es = *(const long*)&e_cur[(size_t)u*128 + c];
            const float w = (uc < 0) ? inv[u] : 1.0f;
            a += fp8x8tof32(es) * w;
        }
        a *= inv[v];
        *(long*)&e_nxt[(size_t)v*128 + c] = f32x8tofp8(a);
    }
}

// ---------------------------------------------------------------------------
// Gather MFMA attention body — all-fp8 table, DPP softmax reduce.
// ---------------------------------------------------------------------------
struct TileRegs { int4 v0; long qf[4], kf[4]; };

__device__ __forceinline__ void load_tile(
    const unsigned char* __restrict__ WQKV, int w, int quad, TileRegs& t)
{
    const unsigned char* row = WQKV + (size_t)w * 192;
    t.v0 = *(const int4*)(row + 128 + quad*16);
    #pragma unroll
    for (int h = 0; h < 4; ++h) {
        if (quad < 2) {
            t.kf[h] = *(const long*)(row +      h*16 + quad*8);
            t.qf[h] = *(const long*)(row + 64 + h*16 + quad*8);
        } else {
            t.kf[h] = 0; t.qf[h] = 0;
        }
    }
}

template<int L, int MODE>
__device__ __forceinline__ void attn_body(
    unsigned char* __restrict__ smem,
    const unsigned char* __restrict__ WQKV, const int* __restrict__ words,
    const short* __restrict__ WoT, const float* __restrict__ bo,
    int N, void* __restrict__ outp, const int* __restrict__ sidx, int bid)
{
    constexpr int SPT = 16 / L;
    constexpr int SB  = 16 * SPT;
    unsigned char (*v_s)[16*80] = (unsigned char (*)[16*80])smem;
    float (*pbar_s)[64]         = (float (*)[64])(smem + 5120);
    float (*mo_s)[68]           = (float (*)[68])(smem + 6144);

    const int wave = threadIdx.x >> 6;
    const int lane = threadIdx.x & 63;
    const int quad = lane >> 4;
    const int lm   = lane & 15;
    const int tok_total = N * L;
    const float invL = 1.0f / ((float)L * QK_SCALE);

    int wid[4];
    #pragma unroll
    for (int t = 0; t < 4; ++t) {
        int tg = (bid*16 + wave*4 + t)*16 + lm;
        if (tg >= tok_total) tg = tok_total - 1;
        wid[t] = words[tg];
    }

    TileRegs cur, nxt;
    load_tile(WQKV, wid[0], quad, cur);

    #pragma unroll
    for (int ti = 0; ti < 4; ++ti) {
        if (ti < 3) load_tile(WQKV, wid[ti+1], quad, nxt);

        *(int4*)&v_s[wave][lm*80 + quad*16] = cur.v0;

        const bool mvalid = (SPT == 1) ? true : ((quad >> 1) == ((lm >> 3) & 1));

        #pragma unroll
        for (int h = 0; h < 4; ++h) {
            const f32x4 s4 = __builtin_amdgcn_mfma_f32_16x16x32_fp8_fp8(
                cur.kf[h], cur.qf[h], (f32x4){0.f,0.f,0.f,0.f}, 0, 0, 0);
            float sv0 = s4[0], sv1 = s4[1], sv2 = s4[2], sv3 = s4[3];
            if (!mvalid) { sv0 = sv1 = sv2 = sv3 = -3.0e38f; }
            float p0 = __builtin_amdgcn_exp2f(sv0*EXP2_C),
                  p1 = __builtin_amdgcn_exp2f(sv1*EXP2_C),
                  p2 = __builtin_amdgcn_exp2f(sv2*EXP2_C),
                  p3 = __builtin_amdgcn_exp2f(sv3*EXP2_C);
            float sm = p0+p1+p2+p3;
            sm += __shfl_xor(sm, 16, 64);
            sm += __shfl_xor(sm, 32, 64);
            const float rinv = __builtin_amdgcn_rcpf(sm);
            p0 *= rinv; p1 *= rinv; p2 *= rinv; p3 *= rinv;
            p0 = rowsum16(p0); p1 = rowsum16(p1);
            p2 = rowsum16(p2); p3 = rowsum16(p3);
            if (lm == 0) {
                pbar_s[wave][h*16 + quad*4 + 0] = p0 * invL;
                pbar_s[wave][h*16 + quad*4 + 1] = p1 * invL;
                pbar_s[wave][h*16 + quad*4 + 2] = p2 * invL;
                pbar_s[wave][h*16 + quad*4 + 3] = p3 * invL;
            }
        }

        #pragma unroll
        for (int s = 0; s < SPT; ++s) {
            f32x4 pb[4];
            #pragma unroll
            for (int j = 0; j < 4; ++j)
                pb[j] = *(const f32x4*)&pbar_s[wave][quad*16 + j*4];
            float o = 0.f;
            #pragma unroll
            for (int j2 = 0; j2 < L; ++j2) {
                const int m = s*L + j2;
                o += pb[m >> 2][m & 3] * fp8tof(v_s[wave][m*80 + lane]);
            }
            mo_s[(wave*4+ti)*SPT + s][lane] = o;
        }

        if (ti < 3) {
            cur.v0 = nxt.v0;
            #pragma unroll
            for (int h = 0; h < 4; ++h) { cur.qf[h] = nxt.qf[h]; cur.kf[h] = nxt.kf[h]; }
        }
    }
    __syncthreads();

    const int col = wave*16 + lm;
    const short* bT = WoT + col*64;
    const bf16x8 b0 = *(const bf16x8*)(bT + quad*8);
    const bf16x8 b1 = *(const bf16x8*)(bT + 32 + quad*8);
    const float boc = bo[col];
    #pragma unroll
    for (int rt = 0; rt < SPT; ++rt) {
        const float* ar = mo_s[rt*16 + lm];
        const float4 fA0 = *(const float4*)(ar + quad*8);
        const float4 fA1 = *(const float4*)(ar + quad*8 + 4);
        const float4 fA2 = *(const float4*)(ar + 32 + quad*8);
        const float4 fA3 = *(const float4*)(ar + 32 + quad*8 + 4);
        union { unsigned u[4]; bf16x8 v; } a0, a1;
        a0.u[0] = pack2r(fA0.x, fA0.y); a0.u[1] = pack2r(fA0.z, fA0.w);
        a0.u[2] = pack2r(fA1.x, fA1.y); a0.u[3] = pack2r(fA1.z, fA1.w);
        a1.u[0] = pack2r(fA2.x, fA2.y); a1.u[1] = pack2r(fA2.z, fA2.w);
        a1.u[2] = pack2r(fA3.x, fA3.y); a1.u[3] = pack2r(fA3.z, fA3.w);
        f32x4 c = {boc, boc, boc, boc};
        c = __builtin_amdgcn_mfma_f32_16x16x32_bf16(a0.v, b0, c, 0, 0, 0);
        c = __builtin_amdgcn_mfma_f32_16x16x32_bf16(a1.v, b1, c, 0, 0, 0);
        #pragma unroll
        for (int r = 0; r < 4; ++r) {
            const int seq = bid*SB + rt*16 + quad*4 + r;
            if (seq < N) {
                if (MODE == 0)
                    ((float*)outp)[(size_t)seq*64 + col] = c[r];
                else if (MODE == 1)
                    atomicAdd(&((float*)outp)[(size_t)sidx[seq]*64 + col], c[r]);
                else
                    ((_Float16*)outp)[(size_t)seq*64 + col] = (_Float16)c[r];
            }
        }
    }
}

// ---------------------------------------------------------------------------
// Fused mega-kernels. Rules learned:
//  r8:  never fuse high-VGPR bodies with occupancy-hungry bodies.
//  r9:  block order = schedule order.
//  r11: no nt stores on scattered writes (defeats L2 write-merging).
//  r12: tail-append gives ~0 overlap when the long job >2x machine capacity.
//  r13/r14: interleave short jobs into the LAST window of the long job.
//  r15: frontier expansion is edge-parallel over pur_src/dst — no CSR dep.
// ---------------------------------------------------------------------------

// misc + mark + zero(prof,acc).
__global__ __launch_bounds__(256) void misc_kernel(
    const int* __restrict__ src, const int* __restrict__ dst,
    unsigned* __restrict__ cntC, int EP,
    const int* __restrict__ pdst, unsigned* __restrict__ deg_p, int NR,
    const float* __restrict__ Wo, short* __restrict__ WoT,
    const float* __restrict__ Wq, const float* __restrict__ Wk,
    const float* __restrict__ Wv, short* __restrict__ Wt,
    const int* __restrict__ users, const int* __restrict__ items,
    const int* __restrict__ negs, int B, unsigned* __restrict__ lev,
    int* __restrict__ listS, int* __restrict__ list2, int* __restrict__ list1,
    int* __restrict__ nS, int* __restrict__ n2, int* __restrict__ n1,
    float4* __restrict__ prof_z, float4* __restrict__ acc_z,
    int prof4, int acc4, int nbM0)
{
    if ((int)blockIdx.x >= nbM0) {
        const int z = ((int)blockIdx.x - nbM0)*256 + (int)threadIdx.x;
        const float4 zero4 = {0.f, 0.f, 0.f, 0.f};
        if (z < prof4) prof_z[z] = zero4;
        else if (z - prof4 < acc4) acc_z[z - prof4] = zero4;
        return;
    }
    const int t = blockIdx.x*256 + threadIdx.x;
    if (t < EP) {
        const int s = src[t], d = dst[t];
        atomicAdd(&cntC[d], 1u); atomicAdd(&cntC[s], 1u);
    }
    if (t < NR) atomicAdd(&deg_p[pdst[t]], 1u);
    if (t < 4096) {
        const int j = t >> 6, k = t & 63;
        WoT[j*64 + k] = rtne(Wo[k*64 + j]);
    }
    if (t < 3*4096) {
        const int p = t >> 12, n = (t >> 6) & 63, k = t & 63;
        const float* W = (p==0) ? Wq : (p==1) ? Wk : Wv;
        Wt[t] = rtne(W[k*64 + n]);
    }
    if (t < 3*B) {
        const int which = t / B, b = t - which*B;
        const int v = (which == 0) ? users[b] : (which == 1) ? items[b] : negs[b];
        const unsigned old = atomicMax(&lev[v], 3u);
        if (old < 3u) {
            listS[atomicAdd(nS, 1)] = v;
            list2[atomicAdd(n2, 1)] = v;
            list1[atomicAdd(n1, 1)] = v;
        }
    }
}

#define SCAN_CHUNK 2048

__device__ __forceinline__ void scan_reduce_body(int b,
    const unsigned* __restrict__ cnt, unsigned* __restrict__ part, int n)
{
    const int base = b * SCAN_CHUNK;
    unsigned s = 0;
    #pragma unroll
    for (int i = 0; i < 8; ++i) {
        const int idx = base + i*256 + threadIdx.x;
        if (idx < n) s += cnt[idx];
    }
    #pragma unroll
    for (int off = 1; off < 64; off <<= 1) s += __shfl_xor(s, off, 64);
    __shared__ unsigned wsum[4];
    if ((threadIdx.x & 63) == 0) wsum[threadIdx.x >> 6] = s;
    __syncthreads();
    if (threadIdx.x == 0) part[b] = wsum[0]+wsum[1]+wsum[2]+wsum[3];
}

// {scan_reduce (NB) | prep (high-VGPR) | edge-expand2 (256 grid-stride)}
__global__ __launch_bounds__(256) void mega_scan_prep(
    const unsigned* __restrict__ cnt, unsigned* __restrict__ part, int n, int NB,
    const float* __restrict__ we, const short* __restrict__ Wt,
    const float* __restrict__ bq, const float* __restrict__ bk,
    const float* __restrict__ bv, unsigned char* __restrict__ WQKV, int NW, int nbP,
    const int* __restrict__ src, const int* __restrict__ dst, int EP,
    unsigned* __restrict__ lev,
    int* __restrict__ list2, int* __restrict__ n2,
    int* __restrict__ list1, int* __restrict__ n1)
{
    const int b = blockIdx.x;
    if (b < NB)            scan_reduce_body(b, cnt, part, n);
    else if (b < NB + nbP) prep_body(b - NB, we, Wt, bq, bk, bv, WQKV, NW);
    else                   eexp_body(b - NB - nbP, 256, 2u, src, dst, EP, lev,
                                     list2, n2, list1, n1);
}

__global__ __launch_bounds__(1024) void scan_part_kernel(
    unsigned* __restrict__ part, int NB)
{
    __shared__ unsigned a[1024];
    const int t = threadIdx.x;
    a[t] = (t < NB) ? part[t] : 0u;
    __syncthreads();
    for (int d = 1; d < 1024; d <<= 1) {
        const unsigned xa = (t >= d) ? a[t-d] : 0u;
        __syncthreads();
        a[t] += xa;
        __syncthreads();
    }
    if (t < NB) part[t] = (t > 0) ? a[t-1] : 0u;
}

__global__ __launch_bounds__(256) void scan_final_kernel(
    const unsigned* __restrict__ cnt, const unsigned* __restrict__ part,
    int* __restrict__ off, int* __restrict__ cur, int n)
{
    const int b = blockIdx.x;
    __shared__ unsigned v[SCAN_CHUNK];
    __shared__ unsigned tsum[256];
    const int base = b * SCAN_CHUNK;
    const int t = threadIdx.x;
    #pragma unroll
    for (int i = 0; i < 8; ++i) {
        const int idx = base + i*256 + t;
        v[i*256 + t] = (idx < n) ? cnt[idx] : 0u;
    }
    __syncthreads();
    unsigned s = 0;
    #pragma unroll
    for (int i = 0; i < 8; ++i) s += v[t*8 + i];
    tsum[t] = s;
    __syncthreads();
    for (int d = 1; d < 256; d <<= 1) {
        const unsigned x = (t >= d) ? tsum[t-d] : 0u;
        __syncthreads();
        tsum[t] += x;
        __syncthreads();
    }
    unsigned run = ((t > 0) ? tsum[t-1] : 0u) + part[b];
    #pragma unroll
    for (int i = 0; i < 8; ++i) {
        const int idx = base + t*8 + i;
        if (idx < n) { off[idx] = (int)run; cur[idx] = (int)run; run += v[t*8+i]; }
    }
}

// {attn x3 | {fill, edge-expand1} Bresenham-interleaved into the LAST window}.
__global__ __launch_bounds__(256) void mega_attn(
    const unsigned char* __restrict__ WQKV,
    const int* __restrict__ src, const int* __restrict__ dst,
    const int* __restrict__ qid, int* __restrict__ curC,
    int2* __restrict__ cmb2, int EP, int nbF,
    unsigned* __restrict__ lev, int* __restrict__ list1, int* __restrict__ n1,
    const int* __restrict__ w1, int N1, float* __restrict__ o1,
    const int* __restrict__ sidx1, int nb1,
    const int* __restrict__ w2, int N2, _Float16* __restrict__ o2, int nb2,
    const int* __restrict__ w3, int N3, float* __restrict__ o3,
    const short* __restrict__ WoT, const float* __restrict__ bo)
{
    __shared__ __align__(16) unsigned char smem[6144 + 32*68*4];
    const int b = blockIdx.x;
    const int total = (int)gridDim.x;
    const int nbS = nbF + 128;         // short jobs: fill + exp1(128 strided)
    int W = (3*total)/5;               // interleave window = last 60% of grid
    if (W < nbS) W = nbS;
    const int wstart = total - W;
    int ba = b;
    if (b >= wstart) {
        const int local = b - wstart;
        const int f0 = (int)(((long)local * nbS) / W);
        const int f1 = (int)(((long)(local + 1) * nbS) / W);
        if (f1 > f0) {
            if (f0 < nbF)
                fill_body(f0, src, dst, qid, curC, cmb2, EP);
            else
                eexp_body(f0 - nbF, 128, 1u, src, dst, EP, lev,
                          list1, n1, nullptr, nullptr);
            return;
        }
        ba = b - f0;
    }
    if (ba < nb1)
        attn_body<16,1>(smem, WQKV, w1, WoT, bo, N1, o1, sidx1, ba);
    else if (ba < nb1 + nb2)
        attn_body<8,2>(smem, WQKV, w2, WoT, bo, N2, o2, nullptr, ba - nb1);
    else
        attn_body<8,0>(smem, WQKV, w3, WoT, bo, N3, o3, nullptr, ba - nb1 - nb2);
}

// finalize only (expand1 moved into mega_attn, edge-parallel).
__global__ __launch_bounds__(256) void finalize_kernel(
    const float* __restrict__ emb, const float* __restrict__ prof,
    unsigned char* __restrict__ e8, float* __restrict__ inv,
    const unsigned* __restrict__ deg_p, const unsigned* __restrict__ cntC, int NE)
{
    finalize_body(blockIdx.x, emb, prof, e8, inv, deg_p, cntC, NE);
}

// {prop1+qconst (2048 blocks FIRST) | gather_acc(e0) tail}
__global__ __launch_bounds__(256) void mega_prop1(
    const unsigned char* __restrict__ e_cur, const _Float16* __restrict__ q_h16,
    const float* __restrict__ inv,
    const int* __restrict__ offC, const int* __restrict__ endC,
    const int2* __restrict__ cmb2,
    const int* __restrict__ list1, const int* __restrict__ n1,
    unsigned char* __restrict__ e_nxt, _Float16* __restrict__ qc,
    const int* __restrict__ users, const int* __restrict__ items,
    const int* __restrict__ negs, float* __restrict__ acc, int B)
{
    const int b = blockIdx.x;
    if (b < 2048) prop1_body(b, 2048, e_cur, q_h16, inv, offC, endC, cmb2,
                             list1, n1, e_nxt, qc);
    else          gather_body(b - 2048, e_cur, users, items, negs, acc, B);
}

// {prop2 (512 blocks) | gather_acc(e1)}
__global__ __launch_bounds__(256) void mega_pg(
    const unsigned char* __restrict__ e_cur, const _Float16* __restrict__ qc,
    const float* __restrict__ inv,
    const int* __restrict__ offC, const int* __restrict__ endC,
    const int2* __restrict__ cmb2,
    const int* __restrict__ list2, const int* __restrict__ n2,
    unsigned char* __restrict__ e_nxt,
    const int* __restrict__ users, const int* __restrict__ items,
    const int* __restrict__ negs, float* __restrict__ acc, int B)
{
    const int b = blockIdx.x;
    if (b < 512) prop_list_body(b, 512, e_cur, qc, inv, offC, endC, cmb2,
                                list2, n2, e_nxt);
    else         gather_body(b - 512, e_cur, users, items, negs, acc, B);
}

// Final hop fused into acc, with gather_acc(e2) merged in:
// acc[r] += e2[sel[r]] + e3[sel[r]]  (e3 computed on the fly from e2).
__global__ __launch_bounds__(256) void prop_batch_kernel(
    const unsigned char* __restrict__ e_cur, const _Float16* __restrict__ qc,
    const float* __restrict__ inv,
    const int* __restrict__ offC, const int* __restrict__ endC,
    const int2* __restrict__ cmb2,
    const int* __restrict__ users, const int* __restrict__ items,
    const int* __restrict__ negs, float* __restrict__ acc, int B)
{
    const int t = blockIdx.x*256 + threadIdx.x;
    const int r = t >> 4;
    if (r >= 3*B) return;
    const int c = (t & 15) * 8;
    const int which = r / B, b = r - which*B;
    const int v = (which == 0) ? users[b] : (which == 1) ? items[b] : negs[b];
    f32x8 a = {0.f,0.f,0.f,0.f,0.f,0.f,0.f,0.f};
    if (c >= 64) {
        const half8 q = *(const half8*)&qc[(size_t)v*64 + (c - 64)];
        a = __builtin_convertvector(q, f32x8);
    }
    const int b0 = offC[v], e0 = endC[v];
    int un = (b0 < e0) ? cmb2[b0].x : 0;
    for (int i = b0; i < e0; ++i) {
        const int uc = un;
        if (i + 1 < e0) un = cmb2[i + 1].x;
        const int u = uc & 0x7fffffff;
        const long es = *(const long*)&e_cur[(size_t)u*128 + c];
        const float w = (uc < 0) ? inv[u] : 1.0f;
        a += fp8x8tof32(es) * w;
    }
    a *= inv[v];
    a += fp8x8tof32(*(const long*)&e_cur[(size_t)v*128 + c]);  // merged gather(e2)
    f32x8 ac = *(const f32x8*)&acc[(size_t)r*128 + c];
    ac += a;
    *(f32x8*)&acc[(size_t)r*128 + c] = ac;
}

__global__ __launch_bounds__(128) void loss_kernel(
    const float* __restrict__ acc, const float* __restrict__ qb,
    float* __restrict__ out, int B, float invB)
{
    const int b = blockIdx.x, d = threadIdx.x;
    const float u = acc[(size_t)b*128 + d] * (0.25f / ES_SCALE);
    const float p = u + (d >= 64 ? qb[(size_t)b*64 + (d - 64)] : 0.f);
    const float ei = acc[(size_t)(B + b)*128 + d];
    const float en = acc[(size_t)(2*B + b)*128 + d];
    float x = p * (ei - en) * (0.25f / ES_SCALE);
    #pragma unroll
    for (int off = 1; off < 64; off <<= 1) x += __shfl_xor(x, off, 64);
    __shared__ float wred[2];
    if ((threadIdx.x & 63) == 0) wred[threadIdx.x >> 6] = x;
    __syncthreads();
    if (threadIdx.x == 0) {
        const float xx = wred[0] + wred[1];
        const float ls = fminf(xx, 0.f) - log1pf(expf(-fabsf(xx)));
        atomicAdd(out, -ls * invB);
    }
}

extern "C" void kernel_launch(void* const* d_in, const int* in_sizes, int n_in,
                              void* d_out, int out_size, void* d_ws, size_t ws_size,
                              hipStream_t stream)
{
    const float* word_emb        = (const float*)d_in[0];
    const float* entity_emb      = (const float*)d_in[1];
    const float* Wq = (const float*)d_in[2];  const float* bq = (const float*)d_in[3];
    const float* Wk = (const float*)d_in[4];  const float* bk = (const float*)d_in[5];
    const float* Wv = (const float*)d_in[6];  const float* bv = (const float*)d_in[7];
    const float* Wo = (const float*)d_in[8];  const float* bo = (const float*)d_in[9];
    const int* review_words      = (const int*)d_in[10];
    const int* query_words_graph = (const int*)d_in[11];
    const int* profile_dst       = (const int*)d_in[12];
    const int* pur_src           = (const int*)d_in[13];
    const int* pur_dst           = (const int*)d_in[14];
    const int* pur_qid           = (const int*)d_in[15];
    const int* users             = (const int*)d_in[16];
    const int* items             = (const int*)d_in[17];
    const int* negs              = (const int*)d_in[18];
    const int* query_words       = (const int*)d_in[19];

    const int NW = in_sizes[0]  / 64;
    const int NE = in_sizes[1]  / 64;
    const int NR = in_sizes[10] / 16;
    const int NQ = in_sizes[11] / 8;
    const int EP = in_sizes[13];
    const int B  = in_sizes[16];
    const int NB = CDIV(NE, SCAN_CHUNK);

    char* ws = (char*)d_ws;
    size_t off = 0;
    auto alloc = [&](size_t bytes) -> char* {
        char* q = ws + off; off += (bytes + 255) & ~(size_t)255; return q;
    };
    float*         prof  = (float*)         alloc((size_t)NE*64*4);  // review scatter
    unsigned char* e8A   = (unsigned char*) alloc((size_t)NE*128);   // fp8 ping
    unsigned char* e8B   = (unsigned char*) alloc((size_t)NE*128);   // fp8 pong
    _Float16*      q_h16 = (_Float16*)      alloc((size_t)NQ*64*2);
    float*         qb    = (float*)         alloc((size_t)B*64*4);
    float*         acc   = (float*)         alloc((size_t)3*B*128*4);
    // deg_p/cntC/lev/fcnt contiguous -> single memset
    unsigned*  deg_p   = (unsigned*) alloc((size_t)NE*4);
    unsigned*  cntC    = (unsigned*) alloc((size_t)NE*4);
    unsigned*  lev     = (unsigned*) alloc((size_t)NE*4);
    int*       fcnt    = (int*)      alloc(256);               // nS, n2, n1
    int*       offC    = (int*)      alloc((size_t)NE*4);
    int*       curC    = (int*)      alloc((size_t)NE*4);
    int2*      cmb2    = (int2*)     alloc((size_t)2*EP*8);
    int*       listS   = (int*)      alloc((size_t)3*B*4);
    int*       list2   = (int*)      alloc((size_t)NE*4);
    int*       list1   = (int*)      alloc((size_t)NE*4);
    float*     inv     = (float*)    alloc((size_t)NE*4);
    unsigned*  part    = (unsigned*) alloc((size_t)NB*4);
    short*     WoT     = (short*)    alloc((size_t)64*64*2);
    short*     Wt      = (short*)    alloc((size_t)3*64*64*2);

    if (off > ws_size) return;  // clean bail instead of OOB fault

    // Aliases (stream order makes each safe):
    unsigned char* WQKV = e8A;                  // NW*192 B <= 2*NE*128 B contiguous
    _Float16* qc = (_Float16*)prof;             // written after finalize read prof
    int* nS = fcnt; int* n2 = fcnt + 1; int* n1 = fcnt + 2;

    const size_t zlen = (size_t)((char*)fcnt - (char*)deg_p) + 256;
    hipMemsetAsync(deg_p, 0, zlen, stream);                    // deg_p..lev + fcnt
    hipMemsetAsync(d_out, 0, (size_t)out_size*4, stream);

    // --- P1: counts + transposes + frontier seed + zero(prof,acc) ---------
    const int nbM0  = CDIV(EP, 256);
    const int prof4 = NE*16;            // NE*64 floats / 4
    const int acc4  = 3*B*32;           // 3*B*128 floats / 4
    const int nbZ   = CDIV(prof4 + acc4, 256);
    misc_kernel<<<nbM0 + nbZ, 256, 0, stream>>>(pur_src, pur_dst, cntC, EP,
        profile_dst, deg_p, NR, Wo, WoT, Wq, Wk, Wv, Wt,
        users, items, negs, B, lev, listS, list2, list1, nS, n2, n1,
        (float4*)prof, (float4*)acc, prof4, acc4, nbM0);

    // --- P2: {scan_reduce | prep_wqkv | edge-expand2} ---------------------
    const int nbP = CDIV(CDIV(NW, 16), 16);
    mega_scan_prep<<<NB + nbP + 256, 256, 0, stream>>>(cntC, part, NE, NB,
        word_emb, Wt, bq, bk, bv, WQKV, NW, nbP,
        pur_src, pur_dst, EP, lev, list2, n2, list1, n1);
    scan_part_kernel<<<1, 1024, 0, stream>>>(part, NB);
    scan_final_kernel<<<NB, 256, 0, stream>>>(cntC, part, offC, curC, NE);

    // --- P3: {attn x3 | fill + edge-expand1 interleaved} ------------------
    const int nbF = CDIV(EP, 256);
    const int nb1 = CDIV(NR, 16), nb2 = CDIV(NQ, 32), nb3 = CDIV(B, 32);
    mega_attn<<<nb1 + nb2 + nb3 + nbF + 128, 256, 0, stream>>>(WQKV,
        pur_src, pur_dst, pur_qid, curC, cmb2, EP, nbF,
        lev, list1, n1,
        review_words, NR, prof, profile_dst, nb1,
        query_words_graph, NQ, q_h16, nb2,
        query_words, B, qb, WoT, bo);

    // --- P4: finalize (pure streaming; expansion already done) ------------
    finalize_kernel<<<CDIV(NE*32, 256), 256, 0, stream>>>(
        entity_emb, prof, e8A, inv, deg_p, cntC, NE);

    // --- P5: {prop1+qconst (e1 at S1) | gather_acc(e0)} -------------------
    mega_prop1<<<2048 + CDIV(3*B*16, 256), 256, 0, stream>>>(
        e8A, q_h16, inv, offC, curC, cmb2, list1, n1, e8B, qc,
        users, items, negs, acc, B);

    // --- P6: {prop2 (e2 at S2) | gather_acc(e1)} --------------------------
    mega_pg<<<512 + CDIV(3*B*16, 256), 256, 0, stream>>>(
        e8B, qc, inv, offC, curC, cmb2, list2, n2, e8A,
        users, items, negs, acc, B);

    // --- P7: e3 at S -> acc (with gather_acc(e2) merged) ------------------
    prop_batch_kernel<<<CDIV(3*B*16, 256), 256, 0, stream>>>(e8A, qc, inv,
        offC, curC, cmb2, users, items, negs, acc, B);

    loss_kernel<<<B, 128, 0, stream>>>(acc, qb, (float*)d_out, B, 1.0f / (float)B);
}

// Round 16
// 456.479 us; speedup vs baseline: 1.7530x; 1.7530x over previous
//
#include <hip/hip_runtime.h>
#include <hip/hip_fp8.h>
#include <cstdint>

#define CDIV(a,b) (((a)+(b)-1)/(b))

typedef __attribute__((ext_vector_type(8))) short bf16x8;     // 8 bf16 = 4 VGPRs
typedef __attribute__((ext_vector_type(4))) float f32x4;      // MFMA accumulator
typedef __attribute__((ext_vector_type(8))) float f32x8;
typedef __attribute__((ext_vector_type(4))) _Float16 half4;
typedef __attribute__((ext_vector_type(8))) _Float16 half8;   // 16B fp16 vector

// Q/K/V stored fp8-e4m3 scaled by QK_SCALE.
#define QK_SCALE 32.0f
#define SCORE_SCALE (0.25f / (QK_SCALE * QK_SCALE))
#define EXP2_C (SCORE_SCALE * 1.44269504089f)

// Entity features stored fp8-e4m3 scaled by ES_SCALE.
#define ES_SCALE 64.0f

__device__ __forceinline__ float bf2f(short s) {
    return __builtin_bit_cast(float, ((unsigned)(unsigned short)s) << 16);
}
__device__ __forceinline__ short rtne(float f) {
    const unsigned u = __builtin_bit_cast(unsigned, f);
    return (short)((u + 0x7fffu + ((u >> 16) & 1u)) >> 16);
}
__device__ __forceinline__ unsigned pack2r(float lo, float hi) {
    return (unsigned)(unsigned short)rtne(lo) | ((unsigned)(unsigned short)rtne(hi) << 16);
}
__device__ __forceinline__ float fp8tof(unsigned char b) {
    __hip_fp8_e4m3 t; t.__x = b; return (float)t;
}
__device__ __forceinline__ unsigned char ftofp8(float f) {
    __hip_fp8_e4m3 t(f); return t.__x;
}
__device__ __forceinline__ f32x8 fp8x8tof32(long v) {
    union { long l; unsigned char b[8]; } u; u.l = v;
    f32x8 r;
    #pragma unroll
    for (int j = 0; j < 8; ++j) r[j] = fp8tof(u.b[j]);
    return r;
}
__device__ __forceinline__ long f32x8tofp8(f32x8 a) {
    union { long l; unsigned char b[8]; } u;
    #pragma unroll
    for (int j = 0; j < 8; ++j) u.b[j] = ftofp8(a[j]);
    return u.l;
}

// DPP row-of-16 sum: result valid at (lane&15)==0. VALU-only (no LDS pipe).
template<int CTRL>
__device__ __forceinline__ float dpp_add(float x) {
    const int t = __builtin_amdgcn_update_dpp(0, __builtin_bit_cast(int, x),
                                              CTRL, 0xf, 0xf, true);
    return x + __builtin_bit_cast(float, t);
}
__device__ __forceinline__ float rowsum16(float x) {
    x = dpp_add<0x108>(x);   // row_shl:8
    x = dpp_add<0x104>(x);   // row_shl:4
    x = dpp_add<0x102>(x);   // row_shl:2
    x = dpp_add<0x101>(x);   // row_shl:1
    return x;
}

// ---------------------------------------------------------------------------
// Device bodies (block-range fused dispatch).
// ---------------------------------------------------------------------------

// MFMA prep. Table row (192 B): [K fp8 64B][Q fp8 64B][V fp8 64B].
// High VGPR — only fused with scan_reduce (occupancy-insensitive).
__device__ __forceinline__ void prep_body(int bid,
    const float* __restrict__ we, const short* __restrict__ Wt,
    const float* __restrict__ bq, const float* __restrict__ bk,
    const float* __restrict__ bv, unsigned char* __restrict__ WQKV, int NW)
{
    const int wave = threadIdx.x >> 6;
    const int lane = threadIdx.x & 63;
    const int quad = lane >> 4;
    const int lm   = lane & 15;
    const int ntiles = CDIV(NW, 16);

    bf16x8 bfr[3][4][2];
    #pragma unroll
    for (int p = 0; p < 3; ++p)
        #pragma unroll
        for (int nt = 0; nt < 4; ++nt)
            #pragma unroll
            for (int kh = 0; kh < 2; ++kh)
                bfr[p][nt][kh] = *(const bf16x8*)(Wt + ((p*64 + nt*16 + lm)*64) + kh*32 + quad*8);
    float bias[3][4];
    #pragma unroll
    for (int nt = 0; nt < 4; ++nt) {
        bias[0][nt] = bq[nt*16 + lm];
        bias[1][nt] = bk[nt*16 + lm];
        bias[2][nt] = bv[nt*16 + lm];
    }

    #pragma unroll
    for (int t = 0; t < 4; ++t) {
        const int tile = (bid*4 + wave)*4 + t;
        if (tile >= ntiles) return;
        const int wb = tile*16;
        int w = wb + lm;
        if (w >= NW) w = NW - 1;
        const float* xr = we + (size_t)w*64;
        union { unsigned u[4]; bf16x8 v; } a0, a1;
        const float4 f0 = *(const float4*)(xr + quad*8);
        const float4 f1 = *(const float4*)(xr + quad*8 + 4);
        const float4 f2 = *(const float4*)(xr + 32 + quad*8);
        const float4 f3 = *(const float4*)(xr + 32 + quad*8 + 4);
        a0.u[0] = pack2r(f0.x, f0.y); a0.u[1] = pack2r(f0.z, f0.w);
        a0.u[2] = pack2r(f1.x, f1.y); a0.u[3] = pack2r(f1.z, f1.w);
        a1.u[0] = pack2r(f2.x, f2.y); a1.u[1] = pack2r(f2.z, f2.w);
        a1.u[2] = pack2r(f3.x, f3.y); a1.u[3] = pack2r(f3.z, f3.w);
        if (w == 0) {
            a0.u[0]=0u; a0.u[1]=0u; a0.u[2]=0u; a0.u[3]=0u;
            a1.u[0]=0u; a1.u[1]=0u; a1.u[2]=0u; a1.u[3]=0u;
        }
        #pragma unroll
        for (int p = 0; p < 3; ++p) {
            #pragma unroll
            for (int nt = 0; nt < 4; ++nt) {
                f32x4 c = {bias[p][nt], bias[p][nt], bias[p][nt], bias[p][nt]};
                c = __builtin_amdgcn_mfma_f32_16x16x32_bf16(a0.v, bfr[p][nt][0], c, 0, 0, 0);
                c = __builtin_amdgcn_mfma_f32_16x16x32_bf16(a1.v, bfr[p][nt][1], c, 0, 0, 0);
                #pragma unroll
                for (int r = 0; r < 4; ++r) {
                    const int w2 = wb + quad*4 + r;
                    if (w2 < NW) {
                        unsigned char* rowo = WQKV + (size_t)w2*192;
                        const int base = (p == 2) ? 128 : (p == 0) ? 64 : 0;
                        rowo[base + nt*16 + lm] = ftofp8(c[r] * QK_SCALE);
                    }
                }
            }
        }
    }
}

// Combined CSR fill: int2 entries. dst-side = (src, qid); src-side = (dst|FLAG, 0).
__device__ __forceinline__ void fill_body(int bid,
    const int* __restrict__ src, const int* __restrict__ dst,
    const int* __restrict__ qid,
    int* __restrict__ curC, int2* __restrict__ cmb2, int EP)
{
    const int t = bid*256 + threadIdx.x;
    if (t >= EP) return;
    const int s = src[t], d = dst[t];
    const int p1 = atomicAdd(&curC[d], 1);
    int2 e1; e1.x = s; e1.y = qid[t];
    cmb2[p1] = e1;
    const int p2 = atomicAdd(&curC[s], 1);
    int2 e2; e2.x = d | (int)0x80000000; e2.y = 0;
    cmb2[p2] = e2;
}

__device__ __forceinline__ void expand_body(int bid, int nb, unsigned targ,
    const int* __restrict__ slist, const int* __restrict__ pn,
    const int* __restrict__ offC, const int* __restrict__ endC,
    const int2* __restrict__ cmb2, unsigned* __restrict__ lev,
    int* __restrict__ dl1, int* __restrict__ dn1,
    int* __restrict__ dl2, int* __restrict__ dn2)
{
    const int n = *pn;
    const int stride = nb * 256;
    for (int t = bid*256 + threadIdx.x; t < n; t += stride) {
        const int v = slist[t];
        const int b0 = offC[v], e0 = endC[v];
        for (int i = b0; i < e0; ++i) {
            const int u = cmb2[i].x & 0x7fffffff;
            const unsigned old = atomicMax(&lev[u], targ);
            if (old < targ) {
                dl1[atomicAdd(dn1, 1)] = u;
                if (dl2) dl2[atomicAdd(dn2, 1)] = u;
            }
        }
    }
}

// e8[v] = fp8(ES_SCALE * [entity_emb[v] | prof[v]/max(deg_p,1)]); inv = 1/sqrt(cntC)
__device__ __forceinline__ void finalize_body(int bid,
    const float* __restrict__ emb, const float* __restrict__ prof,
    unsigned char* __restrict__ e8, float* __restrict__ inv,
    const unsigned* __restrict__ deg_p, const unsigned* __restrict__ cntC, int NE)
{
    const int t = bid*256 + threadIdx.x;
    const int v = t >> 5;
    if (v >= NE) return;
    const int c = (t & 31) * 4;
    float4 ev;
    if (c < 64) {
        ev = *(const float4*)&emb[(size_t)v*64 + c];
    } else {
        ev = *(const float4*)&prof[(size_t)v*64 + (c - 64)];
        const unsigned dp = deg_p[v];
        const float r = 1.0f / (float)(dp > 1u ? dp : 1u);
        ev.x *= r; ev.y *= r; ev.z *= r; ev.w *= r;
    }
    union { unsigned u; unsigned char b[4]; } pk;
    pk.b[0] = ftofp8(ev.x * ES_SCALE);
    pk.b[1] = ftofp8(ev.y * ES_SCALE);
    pk.b[2] = ftofp8(ev.z * ES_SCALE);
    pk.b[3] = ftofp8(ev.w * ES_SCALE);
    *(unsigned*)&e8[(size_t)v*128 + c] = pk.u;
    if (c == 0) {
        const unsigned di = cntC[v];
        inv[v] = 1.0f / sqrtf((float)(di > 1u ? di : 1u));
    }
}

// acc[r] += e8[sel[r]] (scaled domain)
__device__ __forceinline__ void gather_body(int bid,
    const unsigned char* __restrict__ e8, const int* __restrict__ users,
    const int* __restrict__ items, const int* __restrict__ negs,
    float* __restrict__ acc, int B)
{
    const int t = bid*256 + threadIdx.x;
    const int r = t >> 4;
    if (r >= 3*B) return;
    const int c = (t & 15) * 8;
    const int which = r / B, b = r - which*B;
    const int idx = (which == 0) ? users[b] : (which == 1) ? items[b] : negs[b];
    const long ev = *(const long*)&e8[(size_t)idx*128 + c];
    f32x8 a = *(const f32x8*)&acc[(size_t)r*128 + c];
    a += fp8x8tof32(ev);
    *(f32x8*)&acc[(size_t)r*128 + c] = a;
}

// Fused e1-prop + qconst over list1: one CSR traversal computes both the
// q-term (dst-side entries, lanes c>=64) and the e-gather term; qc written
// for the later hops, unrounded q-sum seeds the e1 accumulator.
__device__ __forceinline__ void prop1_body(int bid, int nb,
    const unsigned char* __restrict__ e_cur, const _Float16* __restrict__ q_h16,
    const float* __restrict__ inv,
    const int* __restrict__ offC, const int* __restrict__ endC,
    const int2* __restrict__ cmb2,
    const int* __restrict__ list, const int* __restrict__ pn,
    unsigned char* __restrict__ e_nxt, _Float16* __restrict__ qc)
{
    const int n = *pn;
    const int stride = nb * 256;
    for (int t = bid*256 + threadIdx.x; (t >> 4) < n; t += stride) {
        const int v = list[t >> 4];
        const int c = (t & 15) * 8;
        const bool qlane = (c >= 64);
        f32x8 a  = {0.f,0.f,0.f,0.f,0.f,0.f,0.f,0.f};
        f32x8 qa = {0.f,0.f,0.f,0.f,0.f,0.f,0.f,0.f};
        const int b0 = offC[v], e0 = endC[v];
        for (int i = b0; i < e0; ++i) {
            const int2 e = cmb2[i];
            const int u = e.x & 0x7fffffff;
            const float w = (e.x < 0) ? inv[u] : 1.0f;
            a += fp8x8tof32(*(const long*)&e_cur[(size_t)u*128 + c]) * w;
            if (e.x >= 0 && qlane) {
                const half8 qh = *(const half8*)&q_h16[(size_t)e.y*64 + (c - 64)];
                qa += __builtin_convertvector(qh, f32x8) * inv[u];
            }
        }
        if (qlane) {
            qa *= ES_SCALE;
            *(half8*)&qc[(size_t)v*64 + (c - 64)] = __builtin_convertvector(qa, half8);
            a += qa;
        }
        a *= inv[v];
        *(long*)&e_nxt[(size_t)v*128 + c] = f32x8tofp8(a);
    }
}

// Propagate+combine over the merged list (qc precomputed), for e2.
__device__ __forceinline__ void prop_list_body(int bid, int nb,
    const unsigned char* __restrict__ e_cur, const _Float16* __restrict__ qc,
    const float* __restrict__ inv,
    const int* __restrict__ offC, const int* __restrict__ endC,
    const int2* __restrict__ cmb2,
    const int* __restrict__ list, const int* __restrict__ pn,
    unsigned char* __restrict__ e_nxt)
{
    const int n = *pn;
    const int stride = nb * 256;
    for (int t = bid*256 + threadIdx.x; (t >> 4) < n; t += stride) {
        const int v = list[t >> 4];
        const int c = (t & 15) * 8;
        f32x8 a = {0.f,0.f,0.f,0.f,0.f,0.f,0.f,0.f};
        if (c >= 64) {
            const half8 q = *(const half8*)&qc[(size_t)v*64 + (c - 64)];
            a = __builtin_convertvector(q, f32x8);
        }
        const int b0 = offC[v], e0 = endC[v];
        int un = (b0 < e0) ? cmb2[b0].x : 0;
        for (int i = b0; i < e0; ++i) {
            const int uc = un;
            if (i + 1 < e0) un = cmb2[i + 1].x;
            const int u = uc & 0x7fffffff;
            const long es = *(const long*)&e_cur[(size_t)u*128 + c];
            const float w = (uc < 0) ? inv[u] : 1.0f;
            a += fp8x8tof32(es) * w;
        }
        a *= inv[v];
        *(long*)&e_nxt[(size_t)v*128 + c] = f32x8tofp8(a);
    }
}

// ---------------------------------------------------------------------------
// Gather MFMA attention body — all-fp8 table, DPP softmax reduce.
// ---------------------------------------------------------------------------
struct TileRegs { int4 v0; long qf[4], kf[4]; };

__device__ __forceinline__ void load_tile(
    const unsigned char* __restrict__ WQKV, int w, int quad, TileRegs& t)
{
    const unsigned char* row = WQKV + (size_t)w * 192;
    t.v0 = *(const int4*)(row + 128 + quad*16);
    #pragma unroll
    for (int h = 0; h < 4; ++h) {
        if (quad < 2) {
            t.kf[h] = *(const long*)(row +      h*16 + quad*8);
            t.qf[h] = *(const long*)(row + 64 + h*16 + quad*8);
        } else {
            t.kf[h] = 0; t.qf[h] = 0;
        }
    }
}

template<int L, int MODE>
__device__ __forceinline__ void attn_body(
    unsigned char* __restrict__ smem,
    const unsigned char* __restrict__ WQKV, const int* __restrict__ words,
    const short* __restrict__ WoT, const float* __restrict__ bo,
    int N, void* __restrict__ outp, const int* __restrict__ sidx, int bid)
{
    constexpr int SPT = 16 / L;
    constexpr int SB  = 16 * SPT;
    unsigned char (*v_s)[16*80] = (unsigned char (*)[16*80])smem;
    float (*pbar_s)[64]         = (float (*)[64])(smem + 5120);
    float (*mo_s)[68]           = (float (*)[68])(smem + 6144);

    const int wave = threadIdx.x >> 6;
    const int lane = threadIdx.x & 63;
    const int quad = lane >> 4;
    const int lm   = lane & 15;
    const int tok_total = N * L;
    const float invL = 1.0f / ((float)L * QK_SCALE);

    int wid[4];
    #pragma unroll
    for (int t = 0; t < 4; ++t) {
        int tg = (bid*16 + wave*4 + t)*16 + lm;
        if (tg >= tok_total) tg = tok_total - 1;
        wid[t] = words[tg];
    }

    TileRegs cur, nxt;
    load_tile(WQKV, wid[0], quad, cur);

    #pragma unroll
    for (int ti = 0; ti < 4; ++ti) {
        if (ti < 3) load_tile(WQKV, wid[ti+1], quad, nxt);

        *(int4*)&v_s[wave][lm*80 + quad*16] = cur.v0;

        const bool mvalid = (SPT == 1) ? true : ((quad >> 1) == ((lm >> 3) & 1));

        #pragma unroll
        for (int h = 0; h < 4; ++h) {
            const f32x4 s4 = __builtin_amdgcn_mfma_f32_16x16x32_fp8_fp8(
                cur.kf[h], cur.qf[h], (f32x4){0.f,0.f,0.f,0.f}, 0, 0, 0);
            float sv0 = s4[0], sv1 = s4[1], sv2 = s4[2], sv3 = s4[3];
            if (!mvalid) { sv0 = sv1 = sv2 = sv3 = -3.0e38f; }
            float p0 = __builtin_amdgcn_exp2f(sv0*EXP2_C),
                  p1 = __builtin_amdgcn_exp2f(sv1*EXP2_C),
                  p2 = __builtin_amdgcn_exp2f(sv2*EXP2_C),
                  p3 = __builtin_amdgcn_exp2f(sv3*EXP2_C);
            float sm = p0+p1+p2+p3;
            sm += __shfl_xor(sm, 16, 64);
            sm += __shfl_xor(sm, 32, 64);
            const float rinv = __builtin_amdgcn_rcpf(sm);
            p0 *= rinv; p1 *= rinv; p2 *= rinv; p3 *= rinv;
            p0 = rowsum16(p0); p1 = rowsum16(p1);
            p2 = rowsum16(p2); p3 = rowsum16(p3);
            if (lm == 0) {
                pbar_s[wave][h*16 + quad*4 + 0] = p0 * invL;
                pbar_s[wave][h*16 + quad*4 + 1] = p1 * invL;
                pbar_s[wave][h*16 + quad*4 + 2] = p2 * invL;
                pbar_s[wave][h*16 + quad*4 + 3] = p3 * invL;
            }
        }

        #pragma unroll
        for (int s = 0; s < SPT; ++s) {
            f32x4 pb[4];
            #pragma unroll
            for (int j = 0; j < 4; ++j)
                pb[j] = *(const f32x4*)&pbar_s[wave][quad*16 + j*4];
            float o = 0.f;
            #pragma unroll
            for (int j2 = 0; j2 < L; ++j2) {
                const int m = s*L + j2;
                o += pb[m >> 2][m & 3] * fp8tof(v_s[wave][m*80 + lane]);
            }
            mo_s[(wave*4+ti)*SPT + s][lane] = o;
        }

        if (ti < 3) {
            cur.v0 = nxt.v0;
            #pragma unroll
            for (int h = 0; h < 4; ++h) { cur.qf[h] = nxt.qf[h]; cur.kf[h] = nxt.kf[h]; }
        }
    }
    __syncthreads();

    const int col = wave*16 + lm;
    const short* bT = WoT + col*64;
    const bf16x8 b0 = *(const bf16x8*)(bT + quad*8);
    const bf16x8 b1 = *(const bf16x8*)(bT + 32 + quad*8);
    const float boc = bo[col];
    #pragma unroll
    for (int rt = 0; rt < SPT; ++rt) {
        const float* ar = mo_s[rt*16 + lm];
        const float4 fA0 = *(const float4*)(ar + quad*8);
        const float4 fA1 = *(const float4*)(ar + quad*8 + 4);
        const float4 fA2 = *(const float4*)(ar + 32 + quad*8);
        const float4 fA3 = *(const float4*)(ar + 32 + quad*8 + 4);
        union { unsigned u[4]; bf16x8 v; } a0, a1;
        a0.u[0] = pack2r(fA0.x, fA0.y); a0.u[1] = pack2r(fA0.z, fA0.w);
        a0.u[2] = pack2r(fA1.x, fA1.y); a0.u[3] = pack2r(fA1.z, fA1.w);
        a1.u[0] = pack2r(fA2.x, fA2.y); a1.u[1] = pack2r(fA2.z, fA2.w);
        a1.u[2] = pack2r(fA3.x, fA3.y); a1.u[3] = pack2r(fA3.z, fA3.w);
        f32x4 c = {boc, boc, boc, boc};
        c = __builtin_amdgcn_mfma_f32_16x16x32_bf16(a0.v, b0, c, 0, 0, 0);
        c = __builtin_amdgcn_mfma_f32_16x16x32_bf16(a1.v, b1, c, 0, 0, 0);
        #pragma unroll
        for (int r = 0; r < 4; ++r) {
            const int seq = bid*SB + rt*16 + quad*4 + r;
            if (seq < N) {
                if (MODE == 0)
                    ((float*)outp)[(size_t)seq*64 + col] = c[r];
                else if (MODE == 1)
                    atomicAdd(&((float*)outp)[(size_t)sidx[seq]*64 + col], c[r]);
                else
                    ((_Float16*)outp)[(size_t)seq*64 + col] = (_Float16)c[r];
            }
        }
    }
}

// ---------------------------------------------------------------------------
// Fused mega-kernels. Rules learned:
//  r8:  never fuse high-VGPR bodies with occupancy-hungry bodies.
//  r9:  block order = schedule order.
//  r11: no nt stores on scattered writes (defeats L2 write-merging).
//  r12: tail-append gives ~0 overlap when the long job >2x machine capacity.
//  r13/r14: interleave short jobs into the LAST window of the long job.
//  r15: edge-parallel expansion regressed badly (long low-occupancy tail) —
//       CSR-based expansion restored.
// ---------------------------------------------------------------------------

// misc + mark + zero(prof,acc).
__global__ __launch_bounds__(256) void misc_kernel(
    const int* __restrict__ src, const int* __restrict__ dst,
    unsigned* __restrict__ cntC, int EP,
    const int* __restrict__ pdst, unsigned* __restrict__ deg_p, int NR,
    const float* __restrict__ Wo, short* __restrict__ WoT,
    const float* __restrict__ Wq, const float* __restrict__ Wk,
    const float* __restrict__ Wv, short* __restrict__ Wt,
    const int* __restrict__ users, const int* __restrict__ items,
    const int* __restrict__ negs, int B, unsigned* __restrict__ lev,
    int* __restrict__ listS, int* __restrict__ list2, int* __restrict__ list1,
    int* __restrict__ nS, int* __restrict__ n2, int* __restrict__ n1,
    float4* __restrict__ prof_z, float4* __restrict__ acc_z,
    int prof4, int acc4, int nbM0)
{
    if ((int)blockIdx.x >= nbM0) {
        const int z = ((int)blockIdx.x - nbM0)*256 + (int)threadIdx.x;
        const float4 zero4 = {0.f, 0.f, 0.f, 0.f};
        if (z < prof4) prof_z[z] = zero4;
        else if (z - prof4 < acc4) acc_z[z - prof4] = zero4;
        return;
    }
    const int t = blockIdx.x*256 + threadIdx.x;
    if (t < EP) {
        const int s = src[t], d = dst[t];
        atomicAdd(&cntC[d], 1u); atomicAdd(&cntC[s], 1u);
    }
    if (t < NR) atomicAdd(&deg_p[pdst[t]], 1u);
    if (t < 4096) {
        const int j = t >> 6, k = t & 63;
        WoT[j*64 + k] = rtne(Wo[k*64 + j]);
    }
    if (t < 3*4096) {
        const int p = t >> 12, n = (t >> 6) & 63, k = t & 63;
        const float* W = (p==0) ? Wq : (p==1) ? Wk : Wv;
        Wt[t] = rtne(W[k*64 + n]);
    }
    if (t < 3*B) {
        const int which = t / B, b = t - which*B;
        const int v = (which == 0) ? users[b] : (which == 1) ? items[b] : negs[b];
        const unsigned old = atomicMax(&lev[v], 3u);
        if (old < 3u) {
            listS[atomicAdd(nS, 1)] = v;
            list2[atomicAdd(n2, 1)] = v;
            list1[atomicAdd(n1, 1)] = v;
        }
    }
}

#define SCAN_CHUNK 2048

__device__ __forceinline__ void scan_reduce_body(int b,
    const unsigned* __restrict__ cnt, unsigned* __restrict__ part, int n)
{
    const int base = b * SCAN_CHUNK;
    unsigned s = 0;
    #pragma unroll
    for (int i = 0; i < 8; ++i) {
        const int idx = base + i*256 + threadIdx.x;
        if (idx < n) s += cnt[idx];
    }
    #pragma unroll
    for (int off = 1; off < 64; off <<= 1) s += __shfl_xor(s, off, 64);
    __shared__ unsigned wsum[4];
    if ((threadIdx.x & 63) == 0) wsum[threadIdx.x >> 6] = s;
    __syncthreads();
    if (threadIdx.x == 0) part[b] = wsum[0]+wsum[1]+wsum[2]+wsum[3];
}

// {scan_reduce (NB blocks) | prep (high-VGPR, occupancy-insensitive)}
__global__ __launch_bounds__(256) void mega_scan_prep(
    const unsigned* __restrict__ cnt, unsigned* __restrict__ part, int n, int NB,
    const float* __restrict__ we, const short* __restrict__ Wt,
    const float* __restrict__ bq, const float* __restrict__ bk,
    const float* __restrict__ bv, unsigned char* __restrict__ WQKV, int NW)
{
    const int b = blockIdx.x;
    if (b < NB) scan_reduce_body(b, cnt, part, n);
    else        prep_body(b - NB, we, Wt, bq, bk, bv, WQKV, NW);
}

__global__ __launch_bounds__(1024) void scan_part_kernel(
    unsigned* __restrict__ part, int NB)
{
    __shared__ unsigned a[1024];
    const int t = threadIdx.x;
    a[t] = (t < NB) ? part[t] : 0u;
    __syncthreads();
    for (int d = 1; d < 1024; d <<= 1) {
        const unsigned xa = (t >= d) ? a[t-d] : 0u;
        __syncthreads();
        a[t] += xa;
        __syncthreads();
    }
    if (t < NB) part[t] = (t > 0) ? a[t-1] : 0u;
}

__global__ __launch_bounds__(256) void scan_final_kernel(
    const unsigned* __restrict__ cnt, const unsigned* __restrict__ part,
    int* __restrict__ off, int* __restrict__ cur, int n)
{
    const int b = blockIdx.x;
    __shared__ unsigned v[SCAN_CHUNK];
    __shared__ unsigned tsum[256];
    const int base = b * SCAN_CHUNK;
    const int t = threadIdx.x;
    #pragma unroll
    for (int i = 0; i < 8; ++i) {
        const int idx = base + i*256 + t;
        v[i*256 + t] = (idx < n) ? cnt[idx] : 0u;
    }
    __syncthreads();
    unsigned s = 0;
    #pragma unroll
    for (int i = 0; i < 8; ++i) s += v[t*8 + i];
    tsum[t] = s;
    __syncthreads();
    for (int d = 1; d < 256; d <<= 1) {
        const unsigned x = (t >= d) ? tsum[t-d] : 0u;
        __syncthreads();
        tsum[t] += x;
        __syncthreads();
    }
    unsigned run = ((t > 0) ? tsum[t-1] : 0u) + part[b];
    #pragma unroll
    for (int i = 0; i < 8; ++i) {
        const int idx = base + t*8 + i;
        if (idx < n) { off[idx] = (int)run; cur[idx] = (int)run; run += v[t*8+i]; }
    }
}

// {attn x3 | fill Bresenham-interleaved into the LAST window only}:
// early grid = pure attn; fill overlaps the attn tail; cmb2 written late
// stays L2-hot for the downstream CSR consumers.
__global__ __launch_bounds__(256) void mega_attn(
    const unsigned char* __restrict__ WQKV,
    const int* __restrict__ src, const int* __restrict__ dst,
    const int* __restrict__ qid, int* __restrict__ curC,
    int2* __restrict__ cmb2, int EP, int nbF,
    const int* __restrict__ w1, int N1, float* __restrict__ o1,
    const int* __restrict__ sidx1, int nb1,
    const int* __restrict__ w2, int N2, _Float16* __restrict__ o2, int nb2,
    const int* __restrict__ w3, int N3, float* __restrict__ o3,
    const short* __restrict__ WoT, const float* __restrict__ bo)
{
    __shared__ __align__(16) unsigned char smem[6144 + 32*68*4];
    const int b = blockIdx.x;
    const int total = (int)gridDim.x;
    int W = (3*total)/5;               // interleave window = last 60% of grid
    if (W < nbF) W = nbF;
    const int wstart = total - W;
    int ba = b;
    if (b >= wstart) {
        const int local = b - wstart;
        const int f0 = (int)(((long)local * nbF) / W);
        const int f1 = (int)(((long)(local + 1) * nbF) / W);
        if (f1 > f0) {
            fill_body(f0, src, dst, qid, curC, cmb2, EP);
            return;
        }
        ba = b - f0;
    }
    if (ba < nb1)
        attn_body<16,1>(smem, WQKV, w1, WoT, bo, N1, o1, sidx1, ba);
    else if (ba < nb1 + nb2)
        attn_body<8,2>(smem, WQKV, w2, WoT, bo, N2, o2, nullptr, ba - nb1);
    else
        attn_body<8,0>(smem, WQKV, w3, WoT, bo, N3, o3, nullptr, ba - nb1 - nb2);
}

// standalone expand (used for expand2; tiny)
__global__ __launch_bounds__(256) void expand_kernel(
    unsigned targ, const int* __restrict__ slist, const int* __restrict__ pn,
    const int* __restrict__ offC, const int* __restrict__ endC,
    const int2* __restrict__ cmb2, unsigned* __restrict__ lev,
    int* __restrict__ dl1, int* __restrict__ dn1,
    int* __restrict__ dl2, int* __restrict__ dn2)
{
    expand_body(blockIdx.x, gridDim.x, targ, slist, pn, offC, endC, cmb2, lev,
                dl1, dn1, dl2, dn2);
}

// {expand1 (256 blocks first) | finalize_conv}
__global__ __launch_bounds__(256) void mega_final(
    const int* __restrict__ list2, const int* __restrict__ n2,
    const int* __restrict__ offC, const int* __restrict__ endC,
    const int2* __restrict__ cmb2, unsigned* __restrict__ lev,
    int* __restrict__ list1, int* __restrict__ n1,
    const float* __restrict__ emb, const float* __restrict__ prof,
    unsigned char* __restrict__ e8, float* __restrict__ inv,
    const unsigned* __restrict__ deg_p, const unsigned* __restrict__ cntC, int NE)
{
    const int b = blockIdx.x;
    if (b < 256)
        expand_body(b, 256, 1u, list2, n2, offC, endC, cmb2, lev,
                    list1, n1, nullptr, nullptr);
    else
        finalize_body(b - 256, emb, prof, e8, inv, deg_p, cntC, NE);
}

// {prop1+qconst (2048 blocks FIRST) | gather_acc(e0) tail}
__global__ __launch_bounds__(256) void mega_prop1(
    const unsigned char* __restrict__ e_cur, const _Float16* __restrict__ q_h16,
    const float* __restrict__ inv,
    const int* __restrict__ offC, const int* __restrict__ endC,
    const int2* __restrict__ cmb2,
    const int* __restrict__ list1, const int* __restrict__ n1,
    unsigned char* __restrict__ e_nxt, _Float16* __restrict__ qc,
    const int* __restrict__ users, const int* __restrict__ items,
    const int* __restrict__ negs, float* __restrict__ acc, int B)
{
    const int b = blockIdx.x;
    if (b < 2048) prop1_body(b, 2048, e_cur, q_h16, inv, offC, endC, cmb2,
                             list1, n1, e_nxt, qc);
    else          gather_body(b - 2048, e_cur, users, items, negs, acc, B);
}

// {prop2 (512 blocks) | gather_acc(e1)}
__global__ __launch_bounds__(256) void mega_pg(
    const unsigned char* __restrict__ e_cur, const _Float16* __restrict__ qc,
    const float* __restrict__ inv,
    const int* __restrict__ offC, const int* __restrict__ endC,
    const int2* __restrict__ cmb2,
    const int* __restrict__ list2, const int* __restrict__ n2,
    unsigned char* __restrict__ e_nxt,
    const int* __restrict__ users, const int* __restrict__ items,
    const int* __restrict__ negs, float* __restrict__ acc, int B)
{
    const int b = blockIdx.x;
    if (b < 512) prop_list_body(b, 512, e_cur, qc, inv, offC, endC, cmb2,
                                list2, n2, e_nxt);
    else         gather_body(b - 512, e_cur, users, items, negs, acc, B);
}

// Final hop fused into acc, with gather_acc(e2) merged in:
// acc[r] += e2[sel[r]] + e3[sel[r]]  (e3 computed on the fly from e2).
__global__ __launch_bounds__(256) void prop_batch_kernel(
    const unsigned char* __restrict__ e_cur, const _Float16* __restrict__ qc,
    const float* __restrict__ inv,
    const int* __restrict__ offC, const int* __restrict__ endC,
    const int2* __restrict__ cmb2,
    const int* __restrict__ users, const int* __restrict__ items,
    const int* __restrict__ negs, float* __restrict__ acc, int B)
{
    const int t = blockIdx.x*256 + threadIdx.x;
    const int r = t >> 4;
    if (r >= 3*B) return;
    const int c = (t & 15) * 8;
    const int which = r / B, b = r - which*B;
    const int v = (which == 0) ? users[b] : (which == 1) ? items[b] : negs[b];
    f32x8 a = {0.f,0.f,0.f,0.f,0.f,0.f,0.f,0.f};
    if (c >= 64) {
        const half8 q = *(const half8*)&qc[(size_t)v*64 + (c - 64)];
        a = __builtin_convertvector(q, f32x8);
    }
    const int b0 = offC[v], e0 = endC[v];
    int un = (b0 < e0) ? cmb2[b0].x : 0;
    for (int i = b0; i < e0; ++i) {
        const int uc = un;
        if (i + 1 < e0) un = cmb2[i + 1].x;
        const int u = uc & 0x7fffffff;
        const long es = *(const long*)&e_cur[(size_t)u*128 + c];
        const float w = (uc < 0) ? inv[u] : 1.0f;
        a += fp8x8tof32(es) * w;
    }
    a *= inv[v];
    a += fp8x8tof32(*(const long*)&e_cur[(size_t)v*128 + c]);  // merged gather(e2)
    f32x8 ac = *(const f32x8*)&acc[(size_t)r*128 + c];
    ac += a;
    *(f32x8*)&acc[(size_t)r*128 + c] = ac;
}

__global__ __launch_bounds__(128) void loss_kernel(
    const float* __restrict__ acc, const float* __restrict__ qb,
    float* __restrict__ out, int B, float invB)
{
    const int b = blockIdx.x, d = threadIdx.x;
    const float u = acc[(size_t)b*128 + d] * (0.25f / ES_SCALE);
    const float p = u + (d >= 64 ? qb[(size_t)b*64 + (d - 64)] : 0.f);
    const float ei = acc[(size_t)(B + b)*128 + d];
    const float en = acc[(size_t)(2*B + b)*128 + d];
    float x = p * (ei - en) * (0.25f / ES_SCALE);
    #pragma unroll
    for (int off = 1; off < 64; off <<= 1) x += __shfl_xor(x, off, 64);
    __shared__ float wred[2];
    if ((threadIdx.x & 63) == 0) wred[threadIdx.x >> 6] = x;
    __syncthreads();
    if (threadIdx.x == 0) {
        const float xx = wred[0] + wred[1];
        const float ls = fminf(xx, 0.f) - log1pf(expf(-fabsf(xx)));
        atomicAdd(out, -ls * invB);
    }
}

extern "C" void kernel_launch(void* const* d_in, const int* in_sizes, int n_in,
                              void* d_out, int out_size, void* d_ws, size_t ws_size,
                              hipStream_t stream)
{
    const float* word_emb        = (const float*)d_in[0];
    const float* entity_emb      = (const float*)d_in[1];
    const float* Wq = (const float*)d_in[2];  const float* bq = (const float*)d_in[3];
    const float* Wk = (const float*)d_in[4];  const float* bk = (const float*)d_in[5];
    const float* Wv = (const float*)d_in[6];  const float* bv = (const float*)d_in[7];
    const float* Wo = (const float*)d_in[8];  const float* bo = (const float*)d_in[9];
    const int* review_words      = (const int*)d_in[10];
    const int* query_words_graph = (const int*)d_in[11];
    const int* profile_dst       = (const int*)d_in[12];
    const int* pur_src           = (const int*)d_in[13];
    const int* pur_dst           = (const int*)d_in[14];
    const int* pur_qid           = (const int*)d_in[15];
    const int* users             = (const int*)d_in[16];
    const int* items             = (const int*)d_in[17];
    const int* negs              = (const int*)d_in[18];
    const int* query_words       = (const int*)d_in[19];

    const int NW = in_sizes[0]  / 64;
    const int NE = in_sizes[1]  / 64;
    const int NR = in_sizes[10] / 16;
    const int NQ = in_sizes[11] / 8;
    const int EP = in_sizes[13];
    const int B  = in_sizes[16];
    const int NB = CDIV(NE, SCAN_CHUNK);

    char* ws = (char*)d_ws;
    size_t off = 0;
    auto alloc = [&](size_t bytes) -> char* {
        char* q = ws + off; off += (bytes + 255) & ~(size_t)255; return q;
    };
    float*         prof  = (float*)         alloc((size_t)NE*64*4);  // review scatter
    unsigned char* e8A   = (unsigned char*) alloc((size_t)NE*128);   // fp8 ping
    unsigned char* e8B   = (unsigned char*) alloc((size_t)NE*128);   // fp8 pong
    _Float16*      q_h16 = (_Float16*)      alloc((size_t)NQ*64*2);
    float*         qb    = (float*)         alloc((size_t)B*64*4);
    float*         acc   = (float*)         alloc((size_t)3*B*128*4);
    // deg_p/cntC/lev/fcnt contiguous -> single memset
    unsigned*  deg_p   = (unsigned*) alloc((size_t)NE*4);
    unsigned*  cntC    = (unsigned*) alloc((size_t)NE*4);
    unsigned*  lev     = (unsigned*) alloc((size_t)NE*4);
    int*       fcnt    = (int*)      alloc(256);               // nS, n2, n1
    int*       offC    = (int*)      alloc((size_t)NE*4);
    int*       curC    = (int*)      alloc((size_t)NE*4);
    int2*      cmb2    = (int2*)     alloc((size_t)2*EP*8);
    int*       listS   = (int*)      alloc((size_t)3*B*4);
    int*       list2   = (int*)      alloc((size_t)NE*4);
    int*       list1   = (int*)      alloc((size_t)NE*4);
    float*     inv     = (float*)    alloc((size_t)NE*4);
    unsigned*  part    = (unsigned*) alloc((size_t)NB*4);
    short*     WoT     = (short*)    alloc((size_t)64*64*2);
    short*     Wt      = (short*)    alloc((size_t)3*64*64*2);

    if (off > ws_size) return;  // clean bail instead of OOB fault

    // Aliases (stream order makes each safe):
    unsigned char* WQKV = e8A;                  // NW*192 B <= 2*NE*128 B contiguous
    _Float16* qc = (_Float16*)prof;             // written after mega_final read prof
    int* nS = fcnt; int* n2 = fcnt + 1; int* n1 = fcnt + 2;

    const size_t zlen = (size_t)((char*)fcnt - (char*)deg_p) + 256;
    hipMemsetAsync(deg_p, 0, zlen, stream);                    // deg_p..lev + fcnt
    hipMemsetAsync(d_out, 0, (size_t)out_size*4, stream);

    // --- P1: counts + transposes + frontier seed + zero(prof,acc) ---------
    const int nbM0  = CDIV(EP, 256);
    const int prof4 = NE*16;            // NE*64 floats / 4
    const int acc4  = 3*B*32;           // 3*B*128 floats / 4
    const int nbZ   = CDIV(prof4 + acc4, 256);
    misc_kernel<<<nbM0 + nbZ, 256, 0, stream>>>(pur_src, pur_dst, cntC, EP,
        profile_dst, deg_p, NR, Wo, WoT, Wq, Wk, Wv, Wt,
        users, items, negs, B, lev, listS, list2, list1, nS, n2, n1,
        (float4*)prof, (float4*)acc, prof4, acc4, nbM0);

    // --- P2: {scan_reduce | prep_wqkv} ------------------------------------
    const int nbP = CDIV(CDIV(NW, 16), 16);
    mega_scan_prep<<<NB + nbP, 256, 0, stream>>>(cntC, part, NE, NB,
        word_emb, Wt, bq, bk, bv, WQKV, NW);
    scan_part_kernel<<<1, 1024, 0, stream>>>(part, NB);
    scan_final_kernel<<<NB, 256, 0, stream>>>(cntC, part, offC, curC, NE);

    // --- P3: {attn x3 | fill interleaved into last window} ----------------
    const int nbF = CDIV(EP, 256);
    const int nb1 = CDIV(NR, 16), nb2 = CDIV(NQ, 32), nb3 = CDIV(B, 32);
    mega_attn<<<nb1 + nb2 + nb3 + nbF, 256, 0, stream>>>(WQKV,
        pur_src, pur_dst, pur_qid, curC, cmb2, EP, nbF,
        review_words, NR, prof, profile_dst, nb1,
        query_words_graph, NQ, q_h16, nb2,
        query_words, B, qb, WoT, bo);

    // --- P4: expand2 (tiny, needs cmb2 complete) --------------------------
    expand_kernel<<<64, 256, 0, stream>>>(2u, listS, nS, offC, curC, cmb2, lev,
        list2, n2, list1, n1);

    // --- P5: {expand1 | finalize_conv} ------------------------------------
    mega_final<<<256 + CDIV(NE*32, 256), 256, 0, stream>>>(
        list2, n2, offC, curC, cmb2, lev, list1, n1,
        entity_emb, prof, e8A, inv, deg_p, cntC, NE);

    // --- P6: {prop1+qconst (e1 at S1) | gather_acc(e0)} -------------------
    mega_prop1<<<2048 + CDIV(3*B*16, 256), 256, 0, stream>>>(
        e8A, q_h16, inv, offC, curC, cmb2, list1, n1, e8B, qc,
        users, items, negs, acc, B);

    // --- P7: {prop2 (e2 at S2) | gather_acc(e1)} --------------------------
    mega_pg<<<512 + CDIV(3*B*16, 256), 256, 0, stream>>>(
        e8B, qc, inv, offC, curC, cmb2, list2, n2, e8A,
        users, items, negs, acc, B);

    // --- P8: e3 at S -> acc (with gather_acc(e2) merged) ------------------
    prop_batch_kernel<<<CDIV(3*B*16, 256), 256, 0, stream>>>(e8A, qc, inv,
        offC, curC, cmb2, users, items, negs, acc, B);

    loss_kernel<<<B, 128, 0, stream>>>(acc, qb, (float*)d_out, B, 1.0f / (float)B);
}

// Round 17
// 436.876 us; speedup vs baseline: 1.8316x; 1.0449x over previous
//
#include <hip/hip_runtime.h>
#include <hip/hip_fp8.h>
#include <cstdint>

#define CDIV(a,b) (((a)+(b)-1)/(b))

typedef __attribute__((ext_vector_type(8))) short bf16x8;     // 8 bf16 = 4 VGPRs
typedef __attribute__((ext_vector_type(4))) float f32x4;      // MFMA accumulator
typedef __attribute__((ext_vector_type(8))) float f32x8;
typedef __attribute__((ext_vector_type(4))) _Float16 half4;
typedef __attribute__((ext_vector_type(8))) _Float16 half8;   // 16B fp16 vector

// Q/K/V stored fp8-e4m3 scaled by QK_SCALE.
#define QK_SCALE 32.0f
#define SCORE_SCALE (0.25f / (QK_SCALE * QK_SCALE))
#define EXP2_C (SCORE_SCALE * 1.44269504089f)

// Entity features stored fp8-e4m3 scaled by ES_SCALE.
#define ES_SCALE 64.0f

__device__ __forceinline__ float bf2f(short s) {
    return __builtin_bit_cast(float, ((unsigned)(unsigned short)s) << 16);
}
__device__ __forceinline__ short rtne(float f) {
    const unsigned u = __builtin_bit_cast(unsigned, f);
    return (short)((u + 0x7fffu + ((u >> 16) & 1u)) >> 16);
}
__device__ __forceinline__ unsigned pack2r(float lo, float hi) {
    return (unsigned)(unsigned short)rtne(lo) | ((unsigned)(unsigned short)rtne(hi) << 16);
}
__device__ __forceinline__ float fp8tof(unsigned char b) {
    __hip_fp8_e4m3 t; t.__x = b; return (float)t;
}
__device__ __forceinline__ unsigned char ftofp8(float f) {
    __hip_fp8_e4m3 t(f); return t.__x;
}
__device__ __forceinline__ f32x8 fp8x8tof32(long v) {
    union { long l; unsigned char b[8]; } u; u.l = v;
    f32x8 r;
    #pragma unroll
    for (int j = 0; j < 8; ++j) r[j] = fp8tof(u.b[j]);
    return r;
}
__device__ __forceinline__ long f32x8tofp8(f32x8 a) {
    union { long l; unsigned char b[8]; } u;
    #pragma unroll
    for (int j = 0; j < 8; ++j) u.b[j] = ftofp8(a[j]);
    return u.l;
}

// DPP row-of-16 sum: result valid at (lane&15)==0. VALU-only (no LDS pipe).
template<int CTRL>
__device__ __forceinline__ float dpp_add(float x) {
    const int t = __builtin_amdgcn_update_dpp(0, __builtin_bit_cast(int, x),
                                              CTRL, 0xf, 0xf, true);
    return x + __builtin_bit_cast(float, t);
}
__device__ __forceinline__ float rowsum16(float x) {
    x = dpp_add<0x108>(x);   // row_shl:8
    x = dpp_add<0x104>(x);   // row_shl:4
    x = dpp_add<0x102>(x);   // row_shl:2
    x = dpp_add<0x101>(x);   // row_shl:1
    return x;
}

// ---------------------------------------------------------------------------
// Device bodies (block-range fused dispatch).
// ---------------------------------------------------------------------------

// MFMA prep. Table row (192 B): [K fp8 64B][Q fp8 64B][V fp8 64B].
// High VGPR — only fused with scan_reduce (occupancy-insensitive).
__device__ __forceinline__ void prep_body(int bid,
    const float* __restrict__ we, const short* __restrict__ Wt,
    const float* __restrict__ bq, const float* __restrict__ bk,
    const float* __restrict__ bv, unsigned char* __restrict__ WQKV, int NW)
{
    const int wave = threadIdx.x >> 6;
    const int lane = threadIdx.x & 63;
    const int quad = lane >> 4;
    const int lm   = lane & 15;
    const int ntiles = CDIV(NW, 16);

    bf16x8 bfr[3][4][2];
    #pragma unroll
    for (int p = 0; p < 3; ++p)
        #pragma unroll
        for (int nt = 0; nt < 4; ++nt)
            #pragma unroll
            for (int kh = 0; kh < 2; ++kh)
                bfr[p][nt][kh] = *(const bf16x8*)(Wt + ((p*64 + nt*16 + lm)*64) + kh*32 + quad*8);
    float bias[3][4];
    #pragma unroll
    for (int nt = 0; nt < 4; ++nt) {
        bias[0][nt] = bq[nt*16 + lm];
        bias[1][nt] = bk[nt*16 + lm];
        bias[2][nt] = bv[nt*16 + lm];
    }

    #pragma unroll
    for (int t = 0; t < 4; ++t) {
        const int tile = (bid*4 + wave)*4 + t;
        if (tile >= ntiles) return;
        const int wb = tile*16;
        int w = wb + lm;
        if (w >= NW) w = NW - 1;
        const float* xr = we + (size_t)w*64;
        union { unsigned u[4]; bf16x8 v; } a0, a1;
        const float4 f0 = *(const float4*)(xr + quad*8);
        const float4 f1 = *(const float4*)(xr + quad*8 + 4);
        const float4 f2 = *(const float4*)(xr + 32 + quad*8);
        const float4 f3 = *(const float4*)(xr + 32 + quad*8 + 4);
        a0.u[0] = pack2r(f0.x, f0.y); a0.u[1] = pack2r(f0.z, f0.w);
        a0.u[2] = pack2r(f1.x, f1.y); a0.u[3] = pack2r(f1.z, f1.w);
        a1.u[0] = pack2r(f2.x, f2.y); a1.u[1] = pack2r(f2.z, f2.w);
        a1.u[2] = pack2r(f3.x, f3.y); a1.u[3] = pack2r(f3.z, f3.w);
        if (w == 0) {
            a0.u[0]=0u; a0.u[1]=0u; a0.u[2]=0u; a0.u[3]=0u;
            a1.u[0]=0u; a1.u[1]=0u; a1.u[2]=0u; a1.u[3]=0u;
        }
        #pragma unroll
        for (int p = 0; p < 3; ++p) {
            #pragma unroll
            for (int nt = 0; nt < 4; ++nt) {
                f32x4 c = {bias[p][nt], bias[p][nt], bias[p][nt], bias[p][nt]};
                c = __builtin_amdgcn_mfma_f32_16x16x32_bf16(a0.v, bfr[p][nt][0], c, 0, 0, 0);
                c = __builtin_amdgcn_mfma_f32_16x16x32_bf16(a1.v, bfr[p][nt][1], c, 0, 0, 0);
                #pragma unroll
                for (int r = 0; r < 4; ++r) {
                    const int w2 = wb + quad*4 + r;
                    if (w2 < NW) {
                        unsigned char* rowo = WQKV + (size_t)w2*192;
                        const int base = (p == 2) ? 128 : (p == 0) ? 64 : 0;
                        rowo[base + nt*16 + lm] = ftofp8(c[r] * QK_SCALE);
                    }
                }
            }
        }
    }
}

// Rank-based CSR fill: slot = offC[v] + rank (ranks captured during counting).
// No atomics — one random 4B read + one int2 store per side (r17).
__device__ __forceinline__ void fill_body(int bid,
    const int* __restrict__ src, const int* __restrict__ dst,
    const int* __restrict__ qid,
    const int* __restrict__ offC,
    const int* __restrict__ rankD, const int* __restrict__ rankS,
    int2* __restrict__ cmb2, int EP)
{
    const int t = bid*256 + threadIdx.x;
    if (t >= EP) return;
    const int s = src[t], d = dst[t];
    const int p1 = offC[d] + rankD[t];
    int2 e1; e1.x = s; e1.y = qid[t];
    cmb2[p1] = e1;
    const int p2 = offC[s] + rankS[t];
    int2 e2; e2.x = d | (int)0x80000000; e2.y = 0;
    cmb2[p2] = e2;
}

__device__ __forceinline__ void expand_body(int bid, int nb, unsigned targ,
    const int* __restrict__ slist, const int* __restrict__ pn,
    const int* __restrict__ offC, const int* __restrict__ endC,
    const int2* __restrict__ cmb2, unsigned* __restrict__ lev,
    int* __restrict__ dl1, int* __restrict__ dn1,
    int* __restrict__ dl2, int* __restrict__ dn2)
{
    const int n = *pn;
    const int stride = nb * 256;
    for (int t = bid*256 + threadIdx.x; t < n; t += stride) {
        const int v = slist[t];
        const int b0 = offC[v], e0 = endC[v];
        for (int i = b0; i < e0; ++i) {
            const int u = cmb2[i].x & 0x7fffffff;
            const unsigned old = atomicMax(&lev[u], targ);
            if (old < targ) {
                dl1[atomicAdd(dn1, 1)] = u;
                if (dl2) dl2[atomicAdd(dn2, 1)] = u;
            }
        }
    }
}

// e8[v] = fp8(ES_SCALE * [entity_emb[v] | prof[v]/max(deg_p,1)]); inv = 1/sqrt(cntC)
__device__ __forceinline__ void finalize_body(int bid,
    const float* __restrict__ emb, const float* __restrict__ prof,
    unsigned char* __restrict__ e8, float* __restrict__ inv,
    const unsigned* __restrict__ deg_p, const unsigned* __restrict__ cntC, int NE)
{
    const int t = bid*256 + threadIdx.x;
    const int v = t >> 5;
    if (v >= NE) return;
    const int c = (t & 31) * 4;
    float4 ev;
    if (c < 64) {
        ev = *(const float4*)&emb[(size_t)v*64 + c];
    } else {
        ev = *(const float4*)&prof[(size_t)v*64 + (c - 64)];
        const unsigned dp = deg_p[v];
        const float r = 1.0f / (float)(dp > 1u ? dp : 1u);
        ev.x *= r; ev.y *= r; ev.z *= r; ev.w *= r;
    }
    union { unsigned u; unsigned char b[4]; } pk;
    pk.b[0] = ftofp8(ev.x * ES_SCALE);
    pk.b[1] = ftofp8(ev.y * ES_SCALE);
    pk.b[2] = ftofp8(ev.z * ES_SCALE);
    pk.b[3] = ftofp8(ev.w * ES_SCALE);
    *(unsigned*)&e8[(size_t)v*128 + c] = pk.u;
    if (c == 0) {
        const unsigned di = cntC[v];
        inv[v] = 1.0f / sqrtf((float)(di > 1u ? di : 1u));
    }
}

// acc[r] += e8[sel[r]] (scaled domain)
__device__ __forceinline__ void gather_body(int bid,
    const unsigned char* __restrict__ e8, const int* __restrict__ users,
    const int* __restrict__ items, const int* __restrict__ negs,
    float* __restrict__ acc, int B)
{
    const int t = bid*256 + threadIdx.x;
    const int r = t >> 4;
    if (r >= 3*B) return;
    const int c = (t & 15) * 8;
    const int which = r / B, b = r - which*B;
    const int idx = (which == 0) ? users[b] : (which == 1) ? items[b] : negs[b];
    const long ev = *(const long*)&e8[(size_t)idx*128 + c];
    f32x8 a = *(const f32x8*)&acc[(size_t)r*128 + c];
    a += fp8x8tof32(ev);
    *(f32x8*)&acc[(size_t)r*128 + c] = a;
}

// Fused e1-prop + qconst over list1: one CSR traversal computes both the
// q-term (dst-side entries, lanes c>=64) and the e-gather term; qc written
// for the later hops, unrounded q-sum seeds the e1 accumulator.
__device__ __forceinline__ void prop1_body(int bid, int nb,
    const unsigned char* __restrict__ e_cur, const _Float16* __restrict__ q_h16,
    const float* __restrict__ inv,
    const int* __restrict__ offC, const int* __restrict__ endC,
    const int2* __restrict__ cmb2,
    const int* __restrict__ list, const int* __restrict__ pn,
    unsigned char* __restrict__ e_nxt, _Float16* __restrict__ qc)
{
    const int n = *pn;
    const int stride = nb * 256;
    for (int t = bid*256 + threadIdx.x; (t >> 4) < n; t += stride) {
        const int v = list[t >> 4];
        const int c = (t & 15) * 8;
        const bool qlane = (c >= 64);
        f32x8 a  = {0.f,0.f,0.f,0.f,0.f,0.f,0.f,0.f};
        f32x8 qa = {0.f,0.f,0.f,0.f,0.f,0.f,0.f,0.f};
        const int b0 = offC[v], e0 = endC[v];
        for (int i = b0; i < e0; ++i) {
            const int2 e = cmb2[i];
            const int u = e.x & 0x7fffffff;
            const float w = (e.x < 0) ? inv[u] : 1.0f;
            a += fp8x8tof32(*(const long*)&e_cur[(size_t)u*128 + c]) * w;
            if (e.x >= 0 && qlane) {
                const half8 qh = *(const half8*)&q_h16[(size_t)e.y*64 + (c - 64)];
                qa += __builtin_convertvector(qh, f32x8) * inv[u];
            }
        }
        if (qlane) {
            qa *= ES_SCALE;
            *(half8*)&qc[(size_t)v*64 + (c - 64)] = __builtin_convertvector(qa, half8);
            a += qa;
        }
        a *= inv[v];
        *(long*)&e_nxt[(size_t)v*128 + c] = f32x8tofp8(a);
    }
}

// Propagate+combine over the merged list (qc precomputed), for e2.
__device__ __forceinline__ void prop_list_body(int bid, int nb,
    const unsigned char* __restrict__ e_cur, const _Float16* __restrict__ qc,
    const float* __restrict__ inv,
    const int* __restrict__ offC, const int* __restrict__ endC,
    const int2* __restrict__ cmb2,
    const int* __restrict__ list, const int* __restrict__ pn,
    unsigned char* __restrict__ e_nxt)
{
    const int n = *pn;
    const int stride = nb * 256;
    for (int t = bid*256 + threadIdx.x; (t >> 4) < n; t += stride) {
        const int v = list[t >> 4];
        const int c = (t & 15) * 8;
        f32x8 a = {0.f,0.f,0.f,0.f,0.f,0.f,0.f,0.f};
        if (c >= 64) {
            const half8 q = *(const half8*)&qc[(size_t)v*64 + (c - 64)];
            a = __builtin_convertvector(q, f32x8);
        }
        const int b0 = offC[v], e0 = endC[v];
        int un = (b0 < e0) ? cmb2[b0].x : 0;
        for (int i = b0; i < e0; ++i) {
            const int uc = un;
            if (i + 1 < e0) un = cmb2[i + 1].x;
            const int u = uc & 0x7fffffff;
            const long es = *(const long*)&e_cur[(size_t)u*128 + c];
            const float w = (uc < 0) ? inv[u] : 1.0f;
            a += fp8x8tof32(es) * w;
        }
        a *= inv[v];
        *(long*)&e_nxt[(size_t)v*128 + c] = f32x8tofp8(a);
    }
}

// ---------------------------------------------------------------------------
// Gather MFMA attention body — all-fp8 table, DPP softmax reduce.
// ---------------------------------------------------------------------------
struct TileRegs { int4 v0; long qf[4], kf[4]; };

__device__ __forceinline__ void load_tile(
    const unsigned char* __restrict__ WQKV, int w, int quad, TileRegs& t)
{
    const unsigned char* row = WQKV + (size_t)w * 192;
    t.v0 = *(const int4*)(row + 128 + quad*16);
    #pragma unroll
    for (int h = 0; h < 4; ++h) {
        if (quad < 2) {
            t.kf[h] = *(const long*)(row +      h*16 + quad*8);
            t.qf[h] = *(const long*)(row + 64 + h*16 + quad*8);
        } else {
            t.kf[h] = 0; t.qf[h] = 0;
        }
    }
}

template<int L, int MODE>
__device__ __forceinline__ void attn_body(
    unsigned char* __restrict__ smem,
    const unsigned char* __restrict__ WQKV, const int* __restrict__ words,
    const short* __restrict__ WoT, const float* __restrict__ bo,
    int N, void* __restrict__ outp, const int* __restrict__ sidx, int bid)
{
    constexpr int SPT = 16 / L;
    constexpr int SB  = 16 * SPT;
    unsigned char (*v_s)[16*80] = (unsigned char (*)[16*80])smem;
    float (*pbar_s)[64]         = (float (*)[64])(smem + 5120);
    float (*mo_s)[68]           = (float (*)[68])(smem + 6144);

    const int wave = threadIdx.x >> 6;
    const int lane = threadIdx.x & 63;
    const int quad = lane >> 4;
    const int lm   = lane & 15;
    const int tok_total = N * L;
    const float invL = 1.0f / ((float)L * QK_SCALE);

    int wid[4];
    #pragma unroll
    for (int t = 0; t < 4; ++t) {
        int tg = (bid*16 + wave*4 + t)*16 + lm;
        if (tg >= tok_total) tg = tok_total - 1;
        wid[t] = words[tg];
    }

    TileRegs cur, nxt;
    load_tile(WQKV, wid[0], quad, cur);

    #pragma unroll
    for (int ti = 0; ti < 4; ++ti) {
        if (ti < 3) load_tile(WQKV, wid[ti+1], quad, nxt);

        *(int4*)&v_s[wave][lm*80 + quad*16] = cur.v0;

        const bool mvalid = (SPT == 1) ? true : ((quad >> 1) == ((lm >> 3) & 1));

        #pragma unroll
        for (int h = 0; h < 4; ++h) {
            const f32x4 s4 = __builtin_amdgcn_mfma_f32_16x16x32_fp8_fp8(
                cur.kf[h], cur.qf[h], (f32x4){0.f,0.f,0.f,0.f}, 0, 0, 0);
            float sv0 = s4[0], sv1 = s4[1], sv2 = s4[2], sv3 = s4[3];
            if (!mvalid) { sv0 = sv1 = sv2 = sv3 = -3.0e38f; }
            float p0 = __builtin_amdgcn_exp2f(sv0*EXP2_C),
                  p1 = __builtin_amdgcn_exp2f(sv1*EXP2_C),
                  p2 = __builtin_amdgcn_exp2f(sv2*EXP2_C),
                  p3 = __builtin_amdgcn_exp2f(sv3*EXP2_C);
            float sm = p0+p1+p2+p3;
            sm += __shfl_xor(sm, 16, 64);
            sm += __shfl_xor(sm, 32, 64);
            const float rinv = __builtin_amdgcn_rcpf(sm);
            p0 *= rinv; p1 *= rinv; p2 *= rinv; p3 *= rinv;
            p0 = rowsum16(p0); p1 = rowsum16(p1);
            p2 = rowsum16(p2); p3 = rowsum16(p3);
            if (lm == 0) {
                pbar_s[wave][h*16 + quad*4 + 0] = p0 * invL;
                pbar_s[wave][h*16 + quad*4 + 1] = p1 * invL;
                pbar_s[wave][h*16 + quad*4 + 2] = p2 * invL;
                pbar_s[wave][h*16 + quad*4 + 3] = p3 * invL;
            }
        }

        #pragma unroll
        for (int s = 0; s < SPT; ++s) {
            f32x4 pb[4];
            #pragma unroll
            for (int j = 0; j < 4; ++j)
                pb[j] = *(const f32x4*)&pbar_s[wave][quad*16 + j*4];
            float o = 0.f;
            #pragma unroll
            for (int j2 = 0; j2 < L; ++j2) {
                const int m = s*L + j2;
                o += pb[m >> 2][m & 3] * fp8tof(v_s[wave][m*80 + lane]);
            }
            mo_s[(wave*4+ti)*SPT + s][lane] = o;
        }

        if (ti < 3) {
            cur.v0 = nxt.v0;
            #pragma unroll
            for (int h = 0; h < 4; ++h) { cur.qf[h] = nxt.qf[h]; cur.kf[h] = nxt.kf[h]; }
        }
    }
    __syncthreads();

    const int col = wave*16 + lm;
    const short* bT = WoT + col*64;
    const bf16x8 b0 = *(const bf16x8*)(bT + quad*8);
    const bf16x8 b1 = *(const bf16x8*)(bT + 32 + quad*8);
    const float boc = bo[col];
    #pragma unroll
    for (int rt = 0; rt < SPT; ++rt) {
        const float* ar = mo_s[rt*16 + lm];
        const float4 fA0 = *(const float4*)(ar + quad*8);
        const float4 fA1 = *(const float4*)(ar + quad*8 + 4);
        const float4 fA2 = *(const float4*)(ar + 32 + quad*8);
        const float4 fA3 = *(const float4*)(ar + 32 + quad*8 + 4);
        union { unsigned u[4]; bf16x8 v; } a0, a1;
        a0.u[0] = pack2r(fA0.x, fA0.y); a0.u[1] = pack2r(fA0.z, fA0.w);
        a0.u[2] = pack2r(fA1.x, fA1.y); a0.u[3] = pack2r(fA1.z, fA1.w);
        a1.u[0] = pack2r(fA2.x, fA2.y); a1.u[1] = pack2r(fA2.z, fA2.w);
        a1.u[2] = pack2r(fA3.x, fA3.y); a1.u[3] = pack2r(fA3.z, fA3.w);
        f32x4 c = {boc, boc, boc, boc};
        c = __builtin_amdgcn_mfma_f32_16x16x32_bf16(a0.v, b0, c, 0, 0, 0);
        c = __builtin_amdgcn_mfma_f32_16x16x32_bf16(a1.v, b1, c, 0, 0, 0);
        #pragma unroll
        for (int r = 0; r < 4; ++r) {
            const int seq = bid*SB + rt*16 + quad*4 + r;
            if (seq < N) {
                if (MODE == 0)
                    ((float*)outp)[(size_t)seq*64 + col] = c[r];
                else if (MODE == 1)
                    atomicAdd(&((float*)outp)[(size_t)sidx[seq]*64 + col], c[r]);
                else
                    ((_Float16*)outp)[(size_t)seq*64 + col] = (_Float16)c[r];
            }
        }
    }
}

// ---------------------------------------------------------------------------
// Fused mega-kernels. Rules learned:
//  r8:  never fuse high-VGPR bodies with occupancy-hungry bodies.
//  r9:  block order = schedule order.
//  r11: no nt stores on scattered writes (defeats L2 write-merging).
//  r12: tail-append gives ~0 overlap when the long job >2x machine capacity.
//  r13/r14: interleave short jobs into the LAST window of the long job.
//  r15: no long-running grid-stride scatter loops inside the interleave
//       window (parks CUs at low occupancy).
//  r17: counting atomics' return values ARE the CSR ranks — fill needs no
//       atomics; scan_final writes end-pointers and inlines its own prefix.
// ---------------------------------------------------------------------------

// misc + mark + zero(prof,acc) + rank capture.
__global__ __launch_bounds__(256) void misc_kernel(
    const int* __restrict__ src, const int* __restrict__ dst,
    unsigned* __restrict__ cntC, int* __restrict__ rankD, int* __restrict__ rankS,
    int EP,
    const int* __restrict__ pdst, unsigned* __restrict__ deg_p, int NR,
    const float* __restrict__ Wo, short* __restrict__ WoT,
    const float* __restrict__ Wq, const float* __restrict__ Wk,
    const float* __restrict__ Wv, short* __restrict__ Wt,
    const int* __restrict__ users, const int* __restrict__ items,
    const int* __restrict__ negs, int B, unsigned* __restrict__ lev,
    int* __restrict__ listS, int* __restrict__ list2, int* __restrict__ list1,
    int* __restrict__ nS, int* __restrict__ n2, int* __restrict__ n1,
    float4* __restrict__ prof_z, float4* __restrict__ acc_z,
    int prof4, int acc4, int nbM0)
{
    if ((int)blockIdx.x >= nbM0) {
        const int z = ((int)blockIdx.x - nbM0)*256 + (int)threadIdx.x;
        const float4 zero4 = {0.f, 0.f, 0.f, 0.f};
        if (z < prof4) prof_z[z] = zero4;
        else if (z - prof4 < acc4) acc_z[z - prof4] = zero4;
        return;
    }
    const int t = blockIdx.x*256 + threadIdx.x;
    if (t < EP) {
        const int s = src[t], d = dst[t];
        rankD[t] = (int)atomicAdd(&cntC[d], 1u);
        rankS[t] = (int)atomicAdd(&cntC[s], 1u);
    }
    if (t < NR) atomicAdd(&deg_p[pdst[t]], 1u);
    if (t < 4096) {
        const int j = t >> 6, k = t & 63;
        WoT[j*64 + k] = rtne(Wo[k*64 + j]);
    }
    if (t < 3*4096) {
        const int p = t >> 12, n = (t >> 6) & 63, k = t & 63;
        const float* W = (p==0) ? Wq : (p==1) ? Wk : Wv;
        Wt[t] = rtne(W[k*64 + n]);
    }
    if (t < 3*B) {
        const int which = t / B, b = t - which*B;
        const int v = (which == 0) ? users[b] : (which == 1) ? items[b] : negs[b];
        const unsigned old = atomicMax(&lev[v], 3u);
        if (old < 3u) {
            listS[atomicAdd(nS, 1)] = v;
            list2[atomicAdd(n2, 1)] = v;
            list1[atomicAdd(n1, 1)] = v;
        }
    }
}

#define SCAN_CHUNK 2048

__device__ __forceinline__ void scan_reduce_body(int b,
    const unsigned* __restrict__ cnt, unsigned* __restrict__ part, int n)
{
    const int base = b * SCAN_CHUNK;
    unsigned s = 0;
    #pragma unroll
    for (int i = 0; i < 8; ++i) {
        const int idx = base + i*256 + threadIdx.x;
        if (idx < n) s += cnt[idx];
    }
    #pragma unroll
    for (int off = 1; off < 64; off <<= 1) s += __shfl_xor(s, off, 64);
    __shared__ unsigned wsum[4];
    if ((threadIdx.x & 63) == 0) wsum[threadIdx.x >> 6] = s;
    __syncthreads();
    if (threadIdx.x == 0) part[b] = wsum[0]+wsum[1]+wsum[2]+wsum[3];
}

// {scan_reduce (NB blocks) | prep (high-VGPR, occupancy-insensitive)}
__global__ __launch_bounds__(256) void mega_scan_prep(
    const unsigned* __restrict__ cnt, unsigned* __restrict__ part, int n, int NB,
    const float* __restrict__ we, const short* __restrict__ Wt,
    const float* __restrict__ bq, const float* __restrict__ bk,
    const float* __restrict__ bv, unsigned char* __restrict__ WQKV, int NW)
{
    const int b = blockIdx.x;
    if (b < NB) scan_reduce_body(b, cnt, part, n);
    else        prep_body(b - NB, we, Wt, bq, bk, bv, WQKV, NW);
}

// Final scan pass: inlines its own prefix over part[] (scan_part launch
// eliminated, r17) and writes off = begin, cur = END pointer (fill no
// longer advances curC).
__global__ __launch_bounds__(256) void scan_final_kernel(
    const unsigned* __restrict__ cnt, const unsigned* __restrict__ part,
    int* __restrict__ off, int* __restrict__ cur, int n)
{
    const int b = blockIdx.x;
    __shared__ unsigned v[SCAN_CHUNK];
    __shared__ unsigned tsum[256];
    __shared__ unsigned wsum2[4];
    const int base = b * SCAN_CHUNK;
    const int t = threadIdx.x;
    // inline exclusive prefix base: sum of part[0..b)  (b < NB <= 256)
    unsigned pv = (t < b) ? part[t] : 0u;
    #pragma unroll
    for (int o = 1; o < 64; o <<= 1) pv += __shfl_xor(pv, o, 64);
    if ((t & 63) == 0) wsum2[t >> 6] = pv;
    #pragma unroll
    for (int i = 0; i < 8; ++i) {
        const int idx = base + i*256 + t;
        v[i*256 + t] = (idx < n) ? cnt[idx] : 0u;
    }
    __syncthreads();
    const unsigned pbase = wsum2[0]+wsum2[1]+wsum2[2]+wsum2[3];
    unsigned s = 0;
    #pragma unroll
    for (int i = 0; i < 8; ++i) s += v[t*8 + i];
    tsum[t] = s;
    __syncthreads();
    for (int d = 1; d < 256; d <<= 1) {
        const unsigned x = (t >= d) ? tsum[t-d] : 0u;
        __syncthreads();
        tsum[t] += x;
        __syncthreads();
    }
    unsigned run = ((t > 0) ? tsum[t-1] : 0u) + pbase;
    #pragma unroll
    for (int i = 0; i < 8; ++i) {
        const int idx = base + t*8 + i;
        if (idx < n) {
            const unsigned c = v[t*8+i];
            off[idx] = (int)run;
            cur[idx] = (int)(run + c);   // end pointer
            run += c;
        }
    }
}

// {attn x3 | fill Bresenham-interleaved into the LAST window only}:
// early grid = pure attn; fill overlaps the attn tail; cmb2 written late
// stays L2-hot for the downstream CSR consumers.
__global__ __launch_bounds__(256) void mega_attn(
    const unsigned char* __restrict__ WQKV,
    const int* __restrict__ src, const int* __restrict__ dst,
    const int* __restrict__ qid, const int* __restrict__ offC,
    const int* __restrict__ rankD, const int* __restrict__ rankS,
    int2* __restrict__ cmb2, int EP, int nbF,
    const int* __restrict__ w1, int N1, float* __restrict__ o1,
    const int* __restrict__ sidx1, int nb1,
    const int* __restrict__ w2, int N2, _Float16* __restrict__ o2, int nb2,
    const int* __restrict__ w3, int N3, float* __restrict__ o3,
    const short* __restrict__ WoT, const float* __restrict__ bo)
{
    __shared__ __align__(16) unsigned char smem[6144 + 32*68*4];
    const int b = blockIdx.x;
    const int total = (int)gridDim.x;
    int W = (3*total)/5;               // interleave window = last 60% of grid
    if (W < nbF) W = nbF;
    const int wstart = total - W;
    int ba = b;
    if (b >= wstart) {
        const int local = b - wstart;
        const int f0 = (int)(((long)local * nbF) / W);
        const int f1 = (int)(((long)(local + 1) * nbF) / W);
        if (f1 > f0) {
            fill_body(f0, src, dst, qid, offC, rankD, rankS, cmb2, EP);
            return;
        }
        ba = b - f0;
    }
    if (ba < nb1)
        attn_body<16,1>(smem, WQKV, w1, WoT, bo, N1, o1, sidx1, ba);
    else if (ba < nb1 + nb2)
        attn_body<8,2>(smem, WQKV, w2, WoT, bo, N2, o2, nullptr, ba - nb1);
    else
        attn_body<8,0>(smem, WQKV, w3, WoT, bo, N3, o3, nullptr, ba - nb1 - nb2);
}

// standalone expand (used for expand2; tiny)
__global__ __launch_bounds__(256) void expand_kernel(
    unsigned targ, const int* __restrict__ slist, const int* __restrict__ pn,
    const int* __restrict__ offC, const int* __restrict__ endC,
    const int2* __restrict__ cmb2, unsigned* __restrict__ lev,
    int* __restrict__ dl1, int* __restrict__ dn1,
    int* __restrict__ dl2, int* __restrict__ dn2)
{
    expand_body(blockIdx.x, gridDim.x, targ, slist, pn, offC, endC, cmb2, lev,
                dl1, dn1, dl2, dn2);
}

// {expand1 (256 blocks first) | finalize_conv}
__global__ __launch_bounds__(256) void mega_final(
    const int* __restrict__ list2, const int* __restrict__ n2,
    const int* __restrict__ offC, const int* __restrict__ endC,
    const int2* __restrict__ cmb2, unsigned* __restrict__ lev,
    int* __restrict__ list1, int* __restrict__ n1,
    const float* __restrict__ emb, const float* __restrict__ prof,
    unsigned char* __restrict__ e8, float* __restrict__ inv,
    const unsigned* __restrict__ deg_p, const unsigned* __restrict__ cntC, int NE)
{
    const int b = blockIdx.x;
    if (b < 256)
        expand_body(b, 256, 1u, list2, n2, offC, endC, cmb2, lev,
                    list1, n1, nullptr, nullptr);
    else
        finalize_body(b - 256, emb, prof, e8, inv, deg_p, cntC, NE);
}

// {prop1+qconst (2048 blocks FIRST) | gather_acc(e0) tail}
__global__ __launch_bounds__(256) void mega_prop1(
    const unsigned char* __restrict__ e_cur, const _Float16* __restrict__ q_h16,
    const float* __restrict__ inv,
    const int* __restrict__ offC, const int* __restrict__ endC,
    const int2* __restrict__ cmb2,
    const int* __restrict__ list1, const int* __restrict__ n1,
    unsigned char* __restrict__ e_nxt, _Float16* __restrict__ qc,
    const int* __restrict__ users, const int* __restrict__ items,
    const int* __restrict__ negs, float* __restrict__ acc, int B)
{
    const int b = blockIdx.x;
    if (b < 2048) prop1_body(b, 2048, e_cur, q_h16, inv, offC, endC, cmb2,
                             list1, n1, e_nxt, qc);
    else          gather_body(b - 2048, e_cur, users, items, negs, acc, B);
}

// {prop2 (512 blocks) | gather_acc(e1)}
__global__ __launch_bounds__(256) void mega_pg(
    const unsigned char* __restrict__ e_cur, const _Float16* __restrict__ qc,
    const float* __restrict__ inv,
    const int* __restrict__ offC, const int* __restrict__ endC,
    const int2* __restrict__ cmb2,
    const int* __restrict__ list2, const int* __restrict__ n2,
    unsigned char* __restrict__ e_nxt,
    const int* __restrict__ users, const int* __restrict__ items,
    const int* __restrict__ negs, float* __restrict__ acc, int B)
{
    const int b = blockIdx.x;
    if (b < 512) prop_list_body(b, 512, e_cur, qc, inv, offC, endC, cmb2,
                                list2, n2, e_nxt);
    else         gather_body(b - 512, e_cur, users, items, negs, acc, B);
}

// Final hop fused into acc, with gather_acc(e2) merged in:
// acc[r] += e2[sel[r]] + e3[sel[r]]  (e3 computed on the fly from e2).
__global__ __launch_bounds__(256) void prop_batch_kernel(
    const unsigned char* __restrict__ e_cur, const _Float16* __restrict__ qc,
    const float* __restrict__ inv,
    const int* __restrict__ offC, const int* __restrict__ endC,
    const int2* __restrict__ cmb2,
    const int* __restrict__ users, const int* __restrict__ items,
    const int* __restrict__ negs, float* __restrict__ acc, int B)
{
    const int t = blockIdx.x*256 + threadIdx.x;
    const int r = t >> 4;
    if (r >= 3*B) return;
    const int c = (t & 15) * 8;
    const int which = r / B, b = r - which*B;
    const int v = (which == 0) ? users[b] : (which == 1) ? items[b] : negs[b];
    f32x8 a = {0.f,0.f,0.f,0.f,0.f,0.f,0.f,0.f};
    if (c >= 64) {
        const half8 q = *(const half8*)&qc[(size_t)v*64 + (c - 64)];
        a = __builtin_convertvector(q, f32x8);
    }
    const int b0 = offC[v], e0 = endC[v];
    int un = (b0 < e0) ? cmb2[b0].x : 0;
    for (int i = b0; i < e0; ++i) {
        const int uc = un;
        if (i + 1 < e0) un = cmb2[i + 1].x;
        const int u = uc & 0x7fffffff;
        const long es = *(const long*)&e_cur[(size_t)u*128 + c];
        const float w = (uc < 0) ? inv[u] : 1.0f;
        a += fp8x8tof32(es) * w;
    }
    a *= inv[v];
    a += fp8x8tof32(*(const long*)&e_cur[(size_t)v*128 + c]);  // merged gather(e2)
    f32x8 ac = *(const f32x8*)&acc[(size_t)r*128 + c];
    ac += a;
    *(f32x8*)&acc[(size_t)r*128 + c] = ac;
}

__global__ __launch_bounds__(128) void loss_kernel(
    const float* __restrict__ acc, const float* __restrict__ qb,
    float* __restrict__ out, int B, float invB)
{
    const int b = blockIdx.x, d = threadIdx.x;
    const float u = acc[(size_t)b*128 + d] * (0.25f / ES_SCALE);
    const float p = u + (d >= 64 ? qb[(size_t)b*64 + (d - 64)] : 0.f);
    const float ei = acc[(size_t)(B + b)*128 + d];
    const float en = acc[(size_t)(2*B + b)*128 + d];
    float x = p * (ei - en) * (0.25f / ES_SCALE);
    #pragma unroll
    for (int off = 1; off < 64; off <<= 1) x += __shfl_xor(x, off, 64);
    __shared__ float wred[2];
    if ((threadIdx.x & 63) == 0) wred[threadIdx.x >> 6] = x;
    __syncthreads();
    if (threadIdx.x == 0) {
        const float xx = wred[0] + wred[1];
        const float ls = fminf(xx, 0.f) - log1pf(expf(-fabsf(xx)));
        atomicAdd(out, -ls * invB);
    }
}

extern "C" void kernel_launch(void* const* d_in, const int* in_sizes, int n_in,
                              void* d_out, int out_size, void* d_ws, size_t ws_size,
                              hipStream_t stream)
{
    const float* word_emb        = (const float*)d_in[0];
    const float* entity_emb      = (const float*)d_in[1];
    const float* Wq = (const float*)d_in[2];  const float* bq = (const float*)d_in[3];
    const float* Wk = (const float*)d_in[4];  const float* bk = (const float*)d_in[5];
    const float* Wv = (const float*)d_in[6];  const float* bv = (const float*)d_in[7];
    const float* Wo = (const float*)d_in[8];  const float* bo = (const float*)d_in[9];
    const int* review_words      = (const int*)d_in[10];
    const int* query_words_graph = (const int*)d_in[11];
    const int* profile_dst       = (const int*)d_in[12];
    const int* pur_src           = (const int*)d_in[13];
    const int* pur_dst           = (const int*)d_in[14];
    const int* pur_qid           = (const int*)d_in[15];
    const int* users             = (const int*)d_in[16];
    const int* items             = (const int*)d_in[17];
    const int* negs              = (const int*)d_in[18];
    const int* query_words       = (const int*)d_in[19];

    const int NW = in_sizes[0]  / 64;
    const int NE = in_sizes[1]  / 64;
    const int NR = in_sizes[10] / 16;
    const int NQ = in_sizes[11] / 8;
    const int EP = in_sizes[13];
    const int B  = in_sizes[16];
    const int NB = CDIV(NE, SCAN_CHUNK);

    char* ws = (char*)d_ws;
    size_t off = 0;
    auto alloc = [&](size_t bytes) -> char* {
        char* q = ws + off; off += (bytes + 255) & ~(size_t)255; return q;
    };
    float*         prof  = (float*)         alloc((size_t)NE*64*4);  // review scatter
    unsigned char* e8A   = (unsigned char*) alloc((size_t)NE*128);   // fp8 ping
    unsigned char* e8B   = (unsigned char*) alloc((size_t)NE*128);   // fp8 pong
    _Float16*      q_h16 = (_Float16*)      alloc((size_t)NQ*64*2);
    float*         qb    = (float*)         alloc((size_t)B*64*4);
    float*         acc   = (float*)         alloc((size_t)3*B*128*4);
    // deg_p/cntC/lev/fcnt contiguous -> single memset
    unsigned*  deg_p   = (unsigned*) alloc((size_t)NE*4);
    unsigned*  cntC    = (unsigned*) alloc((size_t)NE*4);
    unsigned*  lev     = (unsigned*) alloc((size_t)NE*4);
    int*       fcnt    = (int*)      alloc(256);               // nS, n2, n1
    int*       offC    = (int*)      alloc((size_t)NE*4);
    int*       curC    = (int*)      alloc((size_t)NE*4);
    int2*      cmb2    = (int2*)     alloc((size_t)2*EP*8);
    int*       rankD   = (int*)      alloc((size_t)EP*4);
    int*       rankS   = (int*)      alloc((size_t)EP*4);
    int*       listS   = (int*)      alloc((size_t)3*B*4);
    int*       list2   = (int*)      alloc((size_t)NE*4);
    int*       list1   = (int*)      alloc((size_t)NE*4);
    float*     inv     = (float*)    alloc((size_t)NE*4);
    unsigned*  part    = (unsigned*) alloc((size_t)NB*4);
    short*     WoT     = (short*)    alloc((size_t)64*64*2);
    short*     Wt      = (short*)    alloc((size_t)3*64*64*2);

    if (off > ws_size) return;  // clean bail instead of OOB fault

    // Aliases (stream order makes each safe):
    unsigned char* WQKV = e8A;                  // NW*192 B <= 2*NE*128 B contiguous
    _Float16* qc = (_Float16*)prof;             // written after mega_final read prof
    int* nS = fcnt; int* n2 = fcnt + 1; int* n1 = fcnt + 2;

    const size_t zlen = (size_t)((char*)fcnt - (char*)deg_p) + 256;
    hipMemsetAsync(deg_p, 0, zlen, stream);                    // deg_p..lev + fcnt
    hipMemsetAsync(d_out, 0, (size_t)out_size*4, stream);

    // --- P1: counts (+rank capture) + transposes + seed + zero(prof,acc) --
    const int nbM0  = CDIV(EP, 256);
    const int prof4 = NE*16;            // NE*64 floats / 4
    const int acc4  = 3*B*32;           // 3*B*128 floats / 4
    const int nbZ   = CDIV(prof4 + acc4, 256);
    misc_kernel<<<nbM0 + nbZ, 256, 0, stream>>>(pur_src, pur_dst, cntC,
        rankD, rankS, EP,
        profile_dst, deg_p, NR, Wo, WoT, Wq, Wk, Wv, Wt,
        users, items, negs, B, lev, listS, list2, list1, nS, n2, n1,
        (float4*)prof, (float4*)acc, prof4, acc4, nbM0);

    // --- P2: {scan_reduce | prep_wqkv} ------------------------------------
    const int nbP = CDIV(CDIV(NW, 16), 16);
    mega_scan_prep<<<NB + nbP, 256, 0, stream>>>(cntC, part, NE, NB,
        word_emb, Wt, bq, bk, bv, WQKV, NW);
    scan_final_kernel<<<NB, 256, 0, stream>>>(cntC, part, offC, curC, NE);

    // --- P3: {attn x3 | rank-fill interleaved into last window} -----------
    const int nbF = CDIV(EP, 256);
    const int nb1 = CDIV(NR, 16), nb2 = CDIV(NQ, 32), nb3 = CDIV(B, 32);
    mega_attn<<<nb1 + nb2 + nb3 + nbF, 256, 0, stream>>>(WQKV,
        pur_src, pur_dst, pur_qid, offC, rankD, rankS, cmb2, EP, nbF,
        review_words, NR, prof, profile_dst, nb1,
        query_words_graph, NQ, q_h16, nb2,
        query_words, B, qb, WoT, bo);

    // --- P4: expand2 (tiny, needs cmb2 complete) --------------------------
    expand_kernel<<<64, 256, 0, stream>>>(2u, listS, nS, offC, curC, cmb2, lev,
        list2, n2, list1, n1);

    // --- P5: {expand1 | finalize_conv} ------------------------------------
    mega_final<<<256 + CDIV(NE*32, 256), 256, 0, stream>>>(
        list2, n2, offC, curC, cmb2, lev, list1, n1,
        entity_emb, prof, e8A, inv, deg_p, cntC, NE);

    // --- P6: {prop1+qconst (e1 at S1) | gather_acc(e0)} -------------------
    mega_prop1<<<2048 + CDIV(3*B*16, 256), 256, 0, stream>>>(
        e8A, q_h16, inv, offC, curC, cmb2, list1, n1, e8B, qc,
        users, items, negs, acc, B);

    // --- P7: {prop2 (e2 at S2) | gather_acc(e1)} --------------------------
    mega_pg<<<512 + CDIV(3*B*16, 256), 256, 0, stream>>>(
        e8B, qc, inv, offC, curC, cmb2, list2, n2, e8A,
        users, items, negs, acc, B);

    // --- P8: e3 at S -> acc (with gather_acc(e2) merged) ------------------
    prop_batch_kernel<<<CDIV(3*B*16, 256), 256, 0, stream>>>(e8A, qc, inv,
        offC, curC, cmb2, users, items, negs, acc, B);

    loss_kernel<<<B, 128, 0, stream>>>(acc, qb, (float*)d_out, B, 1.0f / (float)B);
}